// Round 2
// baseline (3283.631 us; speedup 1.0000x reference)
//
#include <hip/hip_runtime.h>
#include <math.h>

// GuidedUpsampleUnitGF — full fp32 pipeline.
// Stages: upsample+concat -> guide -> gf_stats -> conv1(1x1,relu) ->
//         conv2(5x5,relu) -> guided-filter(fused a/b + box) -> conv3(1x1,relu) -> mask head.
// Workspace ping-pong: A = x(263ch) then p(256ch); B = y1(256ch) then filt(256ch).

#define P2 65536            // 256*256 pixels
#define H2 256
#define W2 256

// ---------------------------------------------------------------- upsample
__global__ void upsample_concat(const float* __restrict__ mask, const float* __restrict__ fg,
                                const float* __restrict__ bg, const float* __restrict__ feat,
                                float* __restrict__ x) {
    int idx = blockIdx.x * 256 + threadIdx.x;          // c*65536 + p, total 263*65536
    int c = idx >> 16;
    int p = idx & 65535;
    int oy = p >> 8, ox = p & 255;
    const float* src;
    if (c == 0)      { src = mask; }
    else if (c < 4)  { src = fg + (c - 1) * 16384; }
    else if (c < 7)  { src = bg + (c - 4) * 16384; }
    else             { src = feat + (c - 7) * 16384; }
    // half-pixel centers, 2x: in = out/2 - 0.25, edge-clamped
    int m = oy >> 1;
    int y0, y1; float wy0;
    if ((oy & 1) == 0) { y0 = (m > 0) ? m - 1 : 0; y1 = m; wy0 = 0.25f; }
    else               { y0 = m; y1 = (m < 127) ? m + 1 : 127; wy0 = 0.75f; }
    float wy1 = 1.0f - wy0;
    int n = ox >> 1;
    int x0, x1; float wx0;
    if ((ox & 1) == 0) { x0 = (n > 0) ? n - 1 : 0; x1 = n; wx0 = 0.25f; }
    else               { x0 = n; x1 = (n < 127) ? n + 1 : 127; wx0 = 0.75f; }
    float wx1 = 1.0f - wx0;
    float v = wy0 * (wx0 * src[y0 * 128 + x0] + wx1 * src[y0 * 128 + x1])
            + wy1 * (wx0 * src[y1 * 128 + x0] + wx1 * src[y1 * 128 + x1]);
    x[idx] = v;
}

// ---------------------------------------------------------------- guide
__global__ void make_guide(const float* __restrict__ x, float* __restrict__ guide) {
    int p = blockIdx.x * 256 + threadIdx.x;
    guide[p] = (x[P2 + p] + x[2 * P2 + p] + x[3 * P2 + p]) * (128.0f / 3.0f);
}

// ---------------------------------------------------------------- guided filter stats
__global__ void gf_stats(const float* __restrict__ guide, float* __restrict__ meanI,
                         float* __restrict__ varI) {
    int p = blockIdx.x * 256 + threadIdx.x;
    int y = p >> 8, xq = p & 255;
    int y0 = (y - 2 > 0) ? y - 2 : 0, y1 = (y + 2 < 255) ? y + 2 : 255;
    int x0 = (xq - 2 > 0) ? xq - 2 : 0, x1 = (xq + 2 < 255) ? xq + 2 : 255;
    float s = 0.f, ss = 0.f;
    for (int yy = y0; yy <= y1; yy++)
        for (int xx = x0; xx <= x1; xx++) {
            float v = guide[yy * 256 + xx];
            s += v; ss += v * v;
        }
    float inv = 1.0f / (float)((y1 - y0 + 1) * (x1 - x0 + 1));
    float m = s * inv;
    meanI[p] = m;
    varI[p] = ss * inv - m * m;
}

// ---------------------------------------------------------------- 1x1 conv as GEMM (+bias+relu)
// Y[oc][p] = relu( sum_k W[oc][k] * X[k][p] + bias[oc] ), X rows of 65536
#define GP 128
#define GOC 64
#define GK 8
__global__ __launch_bounds__(256) void gemm_bias_relu(const float* __restrict__ W,
                                                      const float* __restrict__ X,
                                                      const float* __restrict__ bias,
                                                      float* __restrict__ Y, int K) {
    __shared__ float Wt[GK][GOC];
    __shared__ float Xt[GK][GP];
    int tid = threadIdx.x;
    int pb = blockIdx.x * GP;
    int ob = blockIdx.y * GOC;
    int ocs = tid >> 4;        // 0..15, 4 oc each
    int pxs = tid & 15;        // 0..15, 8 px each
    float acc[4][8];
#pragma unroll
    for (int j = 0; j < 4; j++)
#pragma unroll
        for (int i = 0; i < 8; i++) acc[j][i] = 0.f;

    for (int k0 = 0; k0 < K; k0 += GK) {
        for (int i = tid; i < GK * GOC; i += 256) {
            int kk = i >> 6, oc = i & 63;
            int k = k0 + kk;
            Wt[kk][oc] = (k < K) ? W[(ob + oc) * K + k] : 0.f;
        }
        for (int i = tid; i < GK * GP; i += 256) {
            int kk = i >> 7, px = i & 127;
            int k = k0 + kk;
            Xt[kk][px] = (k < K) ? X[k * P2 + pb + px] : 0.f;
        }
        __syncthreads();
#pragma unroll
        for (int kk = 0; kk < GK; kk++) {
            float w[4], v[8];
#pragma unroll
            for (int j = 0; j < 4; j++) w[j] = Wt[kk][ocs * 4 + j];
#pragma unroll
            for (int i = 0; i < 8; i++) v[i] = Xt[kk][pxs * 8 + i];
#pragma unroll
            for (int j = 0; j < 4; j++)
#pragma unroll
                for (int i = 0; i < 8; i++) acc[j][i] += w[j] * v[i];
        }
        __syncthreads();
    }
#pragma unroll
    for (int j = 0; j < 4; j++) {
        int oc = ob + ocs * 4 + j;
        float bj = bias[oc];
#pragma unroll
        for (int i = 0; i < 8; i++) {
            float v = acc[j][i] + bj;
            Y[oc * P2 + pb + pxs * 8 + i] = (v > 0.f) ? v : 0.f;
        }
    }
}

// ---------------------------------------------------------------- conv2: 5x5, 256->256, pad2, relu
// tile: 32x32 px, 16 oc; thread: 8 px (x) * 8 oc
__global__ __launch_bounds__(256) void conv5x5_relu(const float* __restrict__ in,
                                                    const float* __restrict__ w,   // [oc][ic][25]
                                                    const float* __restrict__ bias,
                                                    float* __restrict__ out) {
    __shared__ float patch[36 * 37];
    __shared__ float wT[25][16];
    int tid = threadIdx.x;
    int gx0 = blockIdx.x * 32;
    int gy0 = blockIdx.y * 32;
    int ob = blockIdx.z * 16;
    int oc_slot = tid >> 7;            // 0..1  (wave-uniform)
    int rem = tid & 127;
    int row = rem >> 2;                // 0..31
    int x0 = (rem & 3) * 8;

    float acc[8][8];
#pragma unroll
    for (int j = 0; j < 8; j++)
#pragma unroll
        for (int i = 0; i < 8; i++) acc[j][i] = 0.f;

    for (int ic = 0; ic < 256; ic++) {
        for (int i = tid; i < 1296; i += 256) {
            int r = i / 36;
            int cc = i - r * 36;
            int gy = gy0 + r - 2, gx = gx0 + cc - 2;
            float v = 0.f;
            if ((unsigned)gy < 256u && (unsigned)gx < 256u) v = in[ic * P2 + gy * 256 + gx];
            patch[r * 37 + cc] = v;
        }
        // 400 entries, 256 threads -> strided loop (tid<400 alone misses taps 16..24!)
        for (int i = tid; i < 400; i += 256) {
            int tap = i >> 4, o = i & 15;
            wT[tap][o] = w[(ob + o) * 6400 + ic * 25 + tap];
        }
        __syncthreads();
#pragma unroll
        for (int dy = 0; dy < 5; dy++) {
#pragma unroll
            for (int dx = 0; dx < 5; dx++) {
                const float* pr = &patch[(row + dy) * 37 + x0 + dx];
                const float* wr = &wT[dy * 5 + dx][oc_slot * 8];
                float pv[8], wv[8];
#pragma unroll
                for (int i = 0; i < 8; i++) pv[i] = pr[i];
#pragma unroll
                for (int j = 0; j < 8; j++) wv[j] = wr[j];
#pragma unroll
                for (int j = 0; j < 8; j++)
#pragma unroll
                    for (int i = 0; i < 8; i++) acc[j][i] += wv[j] * pv[i];
            }
        }
        __syncthreads();
    }
#pragma unroll
    for (int j = 0; j < 8; j++) {
        int oc = ob + oc_slot * 8 + j;
        float bj = bias[oc];
#pragma unroll
        for (int i = 0; i < 8; i++) {
            float v = acc[j][i] + bj;
            out[oc * P2 + (gy0 + row) * 256 + gx0 + x0 + i] = (v > 0.f) ? v : 0.f;
        }
    }
}

// ---------------------------------------------------------------- guided filter fused (a,b + final box)
// per block: 16x16 out tile, one channel
__global__ __launch_bounds__(256) void gf_fused(const float* __restrict__ p,
                                                const float* __restrict__ guide,
                                                const float* __restrict__ meanI,
                                                const float* __restrict__ varI,
                                                float* __restrict__ filt) {
    __shared__ float pP[24 * 25];
    __shared__ float ipP[24 * 25];
    __shared__ float aP[20 * 21];
    __shared__ float bP[20 * 21];
    int tid = threadIdx.x;
    int c = blockIdx.z;
    int gx0 = blockIdx.x * 16, gy0 = blockIdx.y * 16;
    const float* pc = p + c * P2;

    for (int i = tid; i < 576; i += 256) {
        int r = i / 24;
        int cc = i - r * 24;
        int gy = gy0 - 4 + r, gx = gx0 - 4 + cc;
        float pv = 0.f, iv = 0.f;
        if ((unsigned)gy < 256u && (unsigned)gx < 256u) {
            pv = pc[gy * 256 + gx];
            iv = guide[gy * 256 + gx];
        }
        pP[r * 25 + cc] = pv;
        ipP[r * 25 + cc] = iv * pv;
    }
    __syncthreads();

    for (int i = tid; i < 400; i += 256) {
        int r = i / 20;
        int cc = i - r * 20;
        int gy = gy0 - 2 + r, gx = gx0 - 2 + cc;
        float sp = 0.f, sip = 0.f;
#pragma unroll
        for (int dy = 0; dy < 5; dy++)
#pragma unroll
            for (int dx = 0; dx < 5; dx++) {
                sp += pP[(r + dy) * 25 + cc + dx];
                sip += ipP[(r + dy) * 25 + cc + dx];
            }
        float a = 0.f, b = 0.f;
        if ((unsigned)gy < 256u && (unsigned)gx < 256u) {
            int cy = ((gy + 2 < 255) ? gy + 2 : 255) - ((gy - 2 > 0) ? gy - 2 : 0) + 1;
            int cx = ((gx + 2 < 255) ? gx + 2 : 255) - ((gx - 2 > 0) ? gx - 2 : 0) + 1;
            float inv = 1.0f / (float)(cy * cx);
            float mp = sp * inv;
            float mI = meanI[gy * 256 + gx];
            float vI = varI[gy * 256 + gx];
            float cov = sip * inv - mI * mp;
            a = cov / (vI + 0.01f);
            b = mp - a * mI;
        }
        aP[r * 21 + cc] = a;
        bP[r * 21 + cc] = b;
    }
    __syncthreads();

    {
        int r = tid >> 4, cc = tid & 15;
        int gy = gy0 + r, gx = gx0 + cc;
        float sa = 0.f, sb = 0.f;
#pragma unroll
        for (int dy = 0; dy < 5; dy++)
#pragma unroll
            for (int dx = 0; dx < 5; dx++) {
                sa += aP[(r + dy) * 21 + cc + dx];
                sb += bP[(r + dy) * 21 + cc + dx];
            }
        int cy = ((gy + 2 < 255) ? gy + 2 : 255) - ((gy - 2 > 0) ? gy - 2 : 0) + 1;
        int cx = ((gx + 2 < 255) ? gx + 2 : 255) - ((gx - 2 > 0) ? gx - 2 : 0) + 1;
        float inv = 1.0f / (float)(cy * cx);
        float I = guide[gy * 256 + gx];
        filt[c * P2 + gy * 256 + gx] = sa * inv * I + sb * inv;
    }
}

// ---------------------------------------------------------------- mask head (1x1 conv -> sigmoid)
__global__ void mask_head(const float* __restrict__ feat, const float* __restrict__ wm,
                          const float* __restrict__ bm, float* __restrict__ out) {
    int p = blockIdx.x * 256 + threadIdx.x;
    float acc = bm[0];
    for (int c = 0; c < 256; c++) acc += wm[c] * feat[c * P2 + p];
    out[p] = 1.0f / (1.0f + expf(-acc));
}

// ---------------------------------------------------------------- launch
extern "C" void kernel_launch(void* const* d_in, const int* in_sizes, int n_in,
                              void* d_out, int out_size, void* d_ws, size_t ws_size,
                              hipStream_t stream) {
    const float* fg   = (const float*)d_in[0];
    const float* bg   = (const float*)d_in[1];
    const float* mask = (const float*)d_in[2];
    const float* feat = (const float*)d_in[3];
    const float* w1   = (const float*)d_in[4];
    const float* b1   = (const float*)d_in[5];
    const float* w2   = (const float*)d_in[6];
    const float* b2   = (const float*)d_in[7];
    const float* w3   = (const float*)d_in[8];
    const float* b3   = (const float*)d_in[9];
    const float* wm   = (const float*)d_in[10];
    const float* bm   = (const float*)d_in[11];
    float* out = (float*)d_out;
    float* ws  = (float*)d_ws;

    float* A = ws;                       // 263*P2 floats: x, later p
    float* B = A + 263 * P2;             // 256*P2 floats: y1, later filt
    float* guide = B + 256 * P2;         // P2
    float* meanI = guide + P2;           // P2
    float* varI  = meanI + P2;           // P2

    // 1. upsample + concat -> A
    upsample_concat<<<263 * 256, 256, 0, stream>>>(mask, fg, bg, feat, A);
    // 2. guide from fg_2x (channels 1..3 of A)
    make_guide<<<256, 256, 0, stream>>>(A, guide);
    // 3. guide stats
    gf_stats<<<256, 256, 0, stream>>>(guide, meanI, varI);
    // 4. conv1 (1x1, 263->256) + relu : A -> B
    gemm_bias_relu<<<dim3(P2 / GP, 256 / GOC), 256, 0, stream>>>(w1, A, b1, B, 263);
    // 5. conv2 (5x5, 256->256) + relu : B -> A
    conv5x5_relu<<<dim3(8, 8, 16), 256, 0, stream>>>(B, w2, b2, A);
    // 6. guided filter : A (p) -> B (filt)
    gf_fused<<<dim3(16, 16, 256), 256, 0, stream>>>(A, guide, meanI, varI, B);
    // 7. conv3 (1x1, 256->256) + relu : B -> d_out+P2
    gemm_bias_relu<<<dim3(P2 / GP, 256 / GOC), 256, 0, stream>>>(w3, B, b3, out + P2, 256);
    // 8. mask head -> d_out[0..P2)
    mask_head<<<256, 256, 0, stream>>>(out + P2, wm, bm, out);
}

// Round 3
// 1005.119 us; speedup vs baseline: 3.2669x; 3.2669x over previous
//
#include <hip/hip_runtime.h>
#include <hip/hip_bf16.h>
#include <math.h>

// GuidedUpsampleUnitGF — conv2 (5x5, 256->256) rewritten as bf16 MFMA implicit GEMM.
// Pipeline: upsample+concat -> guide -> gf_stats -> border_zero + repack_w2 ->
//           conv1(1x1, fp32 acc, bf16 padded NHWC out) -> conv2 MFMA -> gf -> conv3 -> head.

#define P2 65536            // 256*256 pixels
#define PADW 260            // padded image width/height (2 halo each side; 5x5 needs 2)

typedef short  frag8  __attribute__((ext_vector_type(8)));   // 8 bf16 (4 VGPRs)
typedef float  f32x4  __attribute__((ext_vector_type(4)));

__device__ __forceinline__ void load16_lds(const void* gsrc, void* lds) {
    __builtin_amdgcn_global_load_lds((const __attribute__((address_space(1))) void*)gsrc,
                                     (__attribute__((address_space(3))) void*)lds, 16, 0, 0);
}

// ---------------------------------------------------------------- upsample
__global__ void upsample_concat(const float* __restrict__ mask, const float* __restrict__ fg,
                                const float* __restrict__ bg, const float* __restrict__ feat,
                                float* __restrict__ x) {
    int idx = blockIdx.x * 256 + threadIdx.x;          // c*65536 + p, total 263*65536
    int c = idx >> 16;
    int p = idx & 65535;
    int oy = p >> 8, ox = p & 255;
    const float* src;
    if (c == 0)      { src = mask; }
    else if (c < 4)  { src = fg + (c - 1) * 16384; }
    else if (c < 7)  { src = bg + (c - 4) * 16384; }
    else             { src = feat + (c - 7) * 16384; }
    int m = oy >> 1;
    int y0, y1; float wy0;
    if ((oy & 1) == 0) { y0 = (m > 0) ? m - 1 : 0; y1 = m; wy0 = 0.25f; }
    else               { y0 = m; y1 = (m < 127) ? m + 1 : 127; wy0 = 0.75f; }
    float wy1 = 1.0f - wy0;
    int n = ox >> 1;
    int x0, x1; float wx0;
    if ((ox & 1) == 0) { x0 = (n > 0) ? n - 1 : 0; x1 = n; wx0 = 0.25f; }
    else               { x0 = n; x1 = (n < 127) ? n + 1 : 127; wx0 = 0.75f; }
    float wx1 = 1.0f - wx0;
    float v = wy0 * (wx0 * src[y0 * 128 + x0] + wx1 * src[y0 * 128 + x1])
            + wy1 * (wx0 * src[y1 * 128 + x0] + wx1 * src[y1 * 128 + x1]);
    x[idx] = v;
}

// ---------------------------------------------------------------- guide
__global__ void make_guide(const float* __restrict__ x, float* __restrict__ guide) {
    int p = blockIdx.x * 256 + threadIdx.x;
    guide[p] = (x[P2 + p] + x[2 * P2 + p] + x[3 * P2 + p]) * (128.0f / 3.0f);
}

// ---------------------------------------------------------------- guided filter stats
__global__ void gf_stats(const float* __restrict__ guide, float* __restrict__ meanI,
                         float* __restrict__ varI) {
    int p = blockIdx.x * 256 + threadIdx.x;
    int y = p >> 8, xq = p & 255;
    int y0 = (y - 2 > 0) ? y - 2 : 0, y1 = (y + 2 < 255) ? y + 2 : 255;
    int x0 = (xq - 2 > 0) ? xq - 2 : 0, x1 = (xq + 2 < 255) ? xq + 2 : 255;
    float s = 0.f, ss = 0.f;
    for (int yy = y0; yy <= y1; yy++)
        for (int xx = x0; xx <= x1; xx++) {
            float v = guide[yy * 256 + xx];
            s += v; ss += v * v;
        }
    float inv = 1.0f / (float)((y1 - y0 + 1) * (x1 - x0 + 1));
    float m = s * inv;
    meanI[p] = m;
    varI[p] = ss * inv - m * m;
}

// ---------------------------------------------------------------- zero padded border of y1p
__global__ void border_zero(__hip_bfloat16* __restrict__ y1p) {
    int idx = blockIdx.x * 256 + threadIdx.x;        // pixel*16 chunks; 67600*16 = 1081600
    int p = idx >> 4;
    if (p >= PADW * PADW) return;
    int py = p / PADW, px = p - py * PADW;
    if (py >= 2 && py < 258 && px >= 2 && px < 258) return;
    f32x4 z = {0.f, 0.f, 0.f, 0.f};
    f32x4* dst = (f32x4*)&y1p[(size_t)p * 256 + (idx & 15) * 16];
    dst[0] = z; dst[1] = z;                          // 32 bf16 = 2x16B
}

// ---------------------------------------------------------------- repack w2 -> MFMA B-frag order
// wpk[t][kt][nb][lane][8] : value = w2[oc = nb*16 + (lane&15)][ic = kt*32 + (lane>>4)*8 + j][tap t]
__global__ void repack_w2(const float* __restrict__ w2, __hip_bfloat16* __restrict__ wpk) {
    int idx = blockIdx.x * 256 + threadIdx.x;        // 25*8*16*64 = 204800
    int lane = idx & 63;
    int nb = (idx >> 6) & 15;
    int kt = (idx >> 10) & 7;
    int t  = idx >> 13;
    int oc = nb * 16 + (lane & 15);
    int ic0 = kt * 32 + (lane >> 4) * 8;
    union { __hip_bfloat16 h[8]; f32x4 v; } u;
#pragma unroll
    for (int j = 0; j < 8; j++)
        u.h[j] = __float2bfloat16(w2[(oc * 256 + ic0 + j) * 25 + t]);
    *(f32x4*)&wpk[(size_t)idx * 8] = u.v;
}

// ---------------------------------------------------------------- conv1: 1x1, 263->256, relu, bf16 NHWC padded out
#define GP 128
#define GOC 64
#define GK 8
__global__ __launch_bounds__(256) void conv1_gemm(const float* __restrict__ W,
                                                  const float* __restrict__ X,
                                                  const float* __restrict__ bias,
                                                  __hip_bfloat16* __restrict__ y1p, int K) {
    __shared__ float Wt[GK][GOC];
    __shared__ float Xt[GK][GP];
    int tid = threadIdx.x;
    int pb = blockIdx.x * GP;
    int ob = blockIdx.y * GOC;
    int ocs = tid >> 4;
    int pxs = tid & 15;
    float acc[4][8];
#pragma unroll
    for (int j = 0; j < 4; j++)
#pragma unroll
        for (int i = 0; i < 8; i++) acc[j][i] = 0.f;

    for (int k0 = 0; k0 < K; k0 += GK) {
        for (int i = tid; i < GK * GOC; i += 256) {
            int kk = i >> 6, oc = i & 63;
            int k = k0 + kk;
            Wt[kk][oc] = (k < K) ? W[(ob + oc) * K + k] : 0.f;
        }
        for (int i = tid; i < GK * GP; i += 256) {
            int kk = i >> 7, px = i & 127;
            int k = k0 + kk;
            Xt[kk][px] = (k < K) ? X[k * P2 + pb + px] : 0.f;
        }
        __syncthreads();
#pragma unroll
        for (int kk = 0; kk < GK; kk++) {
            float w[4], v[8];
#pragma unroll
            for (int j = 0; j < 4; j++) w[j] = Wt[kk][ocs * 4 + j];
#pragma unroll
            for (int i = 0; i < 8; i++) v[i] = Xt[kk][pxs * 8 + i];
#pragma unroll
            for (int j = 0; j < 4; j++)
#pragma unroll
                for (int i = 0; i < 8; i++) acc[j][i] += w[j] * v[i];
        }
        __syncthreads();
    }
    // write bf16, pixel-major padded: y1p[(py+2)*260 + px+2][oc], 4 consecutive oc = 8B store
#pragma unroll
    for (int i = 0; i < 8; i++) {
        int p = pb + pxs * 8 + i;
        int py = p >> 8, px = p & 255;
        union { __hip_bfloat16 h[4]; double d; } u;
#pragma unroll
        for (int j = 0; j < 4; j++) {
            float v = acc[j][i] + bias[ob + ocs * 4 + j];
            u.h[j] = __float2bfloat16((v > 0.f) ? v : 0.f);
        }
        *(double*)&y1p[(size_t)((py + 2) * PADW + px + 2) * 256 + ob + ocs * 4] = u.d;
    }
}

// ---------------------------------------------------------------- conv2: 5x5 MFMA implicit GEMM
// block: 128 px (8 rows x 16 cols) x 128 oc; 4 waves, each 4M x 4N of 16x16x32 bf16.
// K-loop: 8 ic-tiles (stage A patch once) x 25 taps (stage B frags, dbuf, 1 barrier/step).
__global__ __launch_bounds__(256) void conv5x5_mfma(const __hip_bfloat16* __restrict__ y1p,
                                                    const __hip_bfloat16* __restrict__ wpk,
                                                    const float* __restrict__ bias,
                                                    float* __restrict__ out) {
    __shared__ __align__(16) __hip_bfloat16 Asm[2][12 * 20 * 32];  // 2 x 15360 B
    __shared__ __align__(16) __hip_bfloat16 Bsm[2][8 * 64 * 8];    // 2 x 8192 B
    const int tid = threadIdx.x;
    const int wave = tid >> 6;
    const int lane = tid & 63;
    const int q = lane >> 4;          // quad
    const int m16 = lane & 15;        // A: pixel-in-strip / B,C: oc-in-tile
    const int wm = wave & 1;          // M-half (rows wm*4..wm*4+3)
    const int wn = wave >> 1;         // N-half (tiles wn*4..wn*4+3)
    const int bx = blockIdx.x, by = blockIdx.y, oh = blockIdx.z;

    f32x4 acc[4][4] = {};

    auto stageA = [&](int ict, int buf) {
        // 960 chunks of 16B: chunk ch -> oct=ch&3, pixel=ch>>2 (pr=pix/20, pc=pix%20)
#pragma unroll
        for (int it = 0; it < 3; it++) {
            int chb = it * 256 + wave * 64;
            int ch = chb + lane;
            int oct = ch & 3, pl = ch >> 2;
            int pc = pl % 20, pr = pl / 20;
            const __hip_bfloat16* src =
                y1p + (size_t)((by * 8 + pr) * PADW + bx * 16 + pc) * 256 + ict * 32 + oct * 8;
            load16_lds(src, &Asm[buf][chb * 8]);
        }
        if (wave < 3) {
            int chb = 768 + wave * 64;
            int ch = chb + lane;
            int oct = ch & 3, pl = ch >> 2;
            int pc = pl % 20, pr = pl / 20;
            const __hip_bfloat16* src =
                y1p + (size_t)((by * 8 + pr) * PADW + bx * 16 + pc) * 256 + ict * 32 + oct * 8;
            load16_lds(src, &Asm[buf][chb * 8]);
        }
    };
    auto stageB = [&](int s, int buf) {
        int ict = s / 25, tap = s - ict * 25;
        const __hip_bfloat16* base = wpk + (size_t)((tap * 8 + ict) * 16 + oh * 8) * 512;
#pragma unroll
        for (int it = 0; it < 2; it++) {
            int chb = it * 256 + wave * 64;
            load16_lds(base + (chb + lane) * 8, &Bsm[buf][chb * 8]);
        }
    };

    stageA(0, 0);
    stageB(0, 0);
    int abuf = 0, bbuf = 0;
    for (int s = 0; s < 200; s++) {
        __syncthreads();                       // drains prev prefetch (vmcnt) + WAR
        int ict = s / 25, tap = s - ict * 25;
        if (s + 1 < 200) stageB(s + 1, bbuf ^ 1);
        if (tap == 24 && ict < 7) stageA(ict + 1, abuf ^ 1);
        int dy = tap / 5, dx = tap - dy * 5;
        frag8 a[4], b[4];
#pragma unroll
        for (int i = 0; i < 4; i++) {
            int r = wm * 4 + i;
            a[i] = *(const frag8*)&Asm[abuf][((r + dy) * 20 + m16 + dx) * 32 + q * 8];
        }
#pragma unroll
        for (int j = 0; j < 4; j++)
            b[j] = *(const frag8*)&Bsm[bbuf][((wn * 4 + j) * 64 + lane) * 8];
#pragma unroll
        for (int i = 0; i < 4; i++)
#pragma unroll
            for (int j = 0; j < 4; j++)
                acc[i][j] = __builtin_amdgcn_mfma_f32_16x16x32_bf16(a[i], b[j], acc[i][j], 0, 0, 0);
        bbuf ^= 1;
        if (tap == 24) abuf ^= 1;
    }

    // epilogue: C/D layout col=lane&15 (oc), row=q*4+reg (pixel-in-strip) -> float4 store
#pragma unroll
    for (int j = 0; j < 4; j++) {
        int oc = oh * 128 + (wn * 4 + j) * 16 + m16;
        float bj = bias[oc];
#pragma unroll
        for (int i = 0; i < 4; i++) {
            int r = wm * 4 + i;
            f32x4 v = acc[i][j];
#pragma unroll
            for (int e = 0; e < 4; e++) {
                float t = v[e] + bj;
                v[e] = (t > 0.f) ? t : 0.f;
            }
            *(f32x4*)&out[(size_t)oc * P2 + (by * 8 + r) * 256 + bx * 16 + q * 4] = v;
        }
    }
}

// ---------------------------------------------------------------- 1x1 conv as GEMM (+bias+relu), fp32 (conv3)
__global__ __launch_bounds__(256) void gemm_bias_relu(const float* __restrict__ W,
                                                      const float* __restrict__ X,
                                                      const float* __restrict__ bias,
                                                      float* __restrict__ Y, int K) {
    __shared__ float Wt[GK][GOC];
    __shared__ float Xt[GK][GP];
    int tid = threadIdx.x;
    int pb = blockIdx.x * GP;
    int ob = blockIdx.y * GOC;
    int ocs = tid >> 4;
    int pxs = tid & 15;
    float acc[4][8];
#pragma unroll
    for (int j = 0; j < 4; j++)
#pragma unroll
        for (int i = 0; i < 8; i++) acc[j][i] = 0.f;

    for (int k0 = 0; k0 < K; k0 += GK) {
        for (int i = tid; i < GK * GOC; i += 256) {
            int kk = i >> 6, oc = i & 63;
            int k = k0 + kk;
            Wt[kk][oc] = (k < K) ? W[(ob + oc) * K + k] : 0.f;
        }
        for (int i = tid; i < GK * GP; i += 256) {
            int kk = i >> 7, px = i & 127;
            int k = k0 + kk;
            Xt[kk][px] = (k < K) ? X[k * P2 + pb + px] : 0.f;
        }
        __syncthreads();
#pragma unroll
        for (int kk = 0; kk < GK; kk++) {
            float w[4], v[8];
#pragma unroll
            for (int j = 0; j < 4; j++) w[j] = Wt[kk][ocs * 4 + j];
#pragma unroll
            for (int i = 0; i < 8; i++) v[i] = Xt[kk][pxs * 8 + i];
#pragma unroll
            for (int j = 0; j < 4; j++)
#pragma unroll
                for (int i = 0; i < 8; i++) acc[j][i] += w[j] * v[i];
        }
        __syncthreads();
    }
#pragma unroll
    for (int j = 0; j < 4; j++) {
        int oc = ob + ocs * 4 + j;
        float bj = bias[oc];
#pragma unroll
        for (int i = 0; i < 8; i++) {
            float v = acc[j][i] + bj;
            Y[oc * P2 + pb + pxs * 8 + i] = (v > 0.f) ? v : 0.f;
        }
    }
}

// ---------------------------------------------------------------- guided filter fused (a,b + final box)
__global__ __launch_bounds__(256) void gf_fused(const float* __restrict__ p,
                                                const float* __restrict__ guide,
                                                const float* __restrict__ meanI,
                                                const float* __restrict__ varI,
                                                float* __restrict__ filt) {
    __shared__ float pP[24 * 25];
    __shared__ float ipP[24 * 25];
    __shared__ float aP[20 * 21];
    __shared__ float bP[20 * 21];
    int tid = threadIdx.x;
    int c = blockIdx.z;
    int gx0 = blockIdx.x * 16, gy0 = blockIdx.y * 16;
    const float* pc = p + c * P2;

    for (int i = tid; i < 576; i += 256) {
        int r = i / 24;
        int cc = i - r * 24;
        int gy = gy0 - 4 + r, gx = gx0 - 4 + cc;
        float pv = 0.f, iv = 0.f;
        if ((unsigned)gy < 256u && (unsigned)gx < 256u) {
            pv = pc[gy * 256 + gx];
            iv = guide[gy * 256 + gx];
        }
        pP[r * 25 + cc] = pv;
        ipP[r * 25 + cc] = iv * pv;
    }
    __syncthreads();

    for (int i = tid; i < 400; i += 256) {
        int r = i / 20;
        int cc = i - r * 20;
        int gy = gy0 - 2 + r, gx = gx0 - 2 + cc;
        float sp = 0.f, sip = 0.f;
#pragma unroll
        for (int dy = 0; dy < 5; dy++)
#pragma unroll
            for (int dx = 0; dx < 5; dx++) {
                sp += pP[(r + dy) * 25 + cc + dx];
                sip += ipP[(r + dy) * 25 + cc + dx];
            }
        float a = 0.f, b = 0.f;
        if ((unsigned)gy < 256u && (unsigned)gx < 256u) {
            int cy = ((gy + 2 < 255) ? gy + 2 : 255) - ((gy - 2 > 0) ? gy - 2 : 0) + 1;
            int cx = ((gx + 2 < 255) ? gx + 2 : 255) - ((gx - 2 > 0) ? gx - 2 : 0) + 1;
            float inv = 1.0f / (float)(cy * cx);
            float mp = sp * inv;
            float mI = meanI[gy * 256 + gx];
            float vI = varI[gy * 256 + gx];
            float cov = sip * inv - mI * mp;
            a = cov / (vI + 0.01f);
            b = mp - a * mI;
        }
        aP[r * 21 + cc] = a;
        bP[r * 21 + cc] = b;
    }
    __syncthreads();

    {
        int r = tid >> 4, cc = tid & 15;
        int gy = gy0 + r, gx = gx0 + cc;
        float sa = 0.f, sb = 0.f;
#pragma unroll
        for (int dy = 0; dy < 5; dy++)
#pragma unroll
            for (int dx = 0; dx < 5; dx++) {
                sa += aP[(r + dy) * 21 + cc + dx];
                sb += bP[(r + dy) * 21 + cc + dx];
            }
        int cy = ((gy + 2 < 255) ? gy + 2 : 255) - ((gy - 2 > 0) ? gy - 2 : 0) + 1;
        int cx = ((gx + 2 < 255) ? gx + 2 : 255) - ((gx - 2 > 0) ? gx - 2 : 0) + 1;
        float inv = 1.0f / (float)(cy * cx);
        float I = guide[gy * 256 + gx];
        filt[c * P2 + gy * 256 + gx] = sa * inv * I + sb * inv;
    }
}

// ---------------------------------------------------------------- mask head (1x1 conv -> sigmoid)
__global__ void mask_head(const float* __restrict__ feat, const float* __restrict__ wm,
                          const float* __restrict__ bm, float* __restrict__ out) {
    int p = blockIdx.x * 256 + threadIdx.x;
    float acc = bm[0];
    for (int c = 0; c < 256; c++) acc += wm[c] * feat[c * P2 + p];
    out[p] = 1.0f / (1.0f + expf(-acc));
}

// ---------------------------------------------------------------- launch
extern "C" void kernel_launch(void* const* d_in, const int* in_sizes, int n_in,
                              void* d_out, int out_size, void* d_ws, size_t ws_size,
                              hipStream_t stream) {
    const float* fg   = (const float*)d_in[0];
    const float* bg   = (const float*)d_in[1];
    const float* mask = (const float*)d_in[2];
    const float* feat = (const float*)d_in[3];
    const float* w1   = (const float*)d_in[4];
    const float* b1   = (const float*)d_in[5];
    const float* w2   = (const float*)d_in[6];
    const float* b2   = (const float*)d_in[7];
    const float* w3   = (const float*)d_in[8];
    const float* b3   = (const float*)d_in[9];
    const float* wm   = (const float*)d_in[10];
    const float* bm   = (const float*)d_in[11];
    float* out = (float*)d_out;
    float* ws  = (float*)d_ws;

    float* A = ws;                               // 263*P2 fp32: x, later conv2 out (p)
    float* B = A + 263 * P2;                     // 256*P2 fp32: filt
    float* guide = B + 256 * P2;                 // P2
    float* meanI = guide + P2;                   // P2
    float* varI  = meanI + P2;                   // P2
    __hip_bfloat16* y1p = (__hip_bfloat16*)(varI + P2);      // 260*260*256 bf16 padded NHWC
    __hip_bfloat16* wpk = y1p + (size_t)PADW * PADW * 256;   // 25*8*16*64*8 bf16

    // 1. upsample + concat -> A
    upsample_concat<<<263 * 256, 256, 0, stream>>>(mask, fg, bg, feat, A);
    // 2. guide + stats
    make_guide<<<256, 256, 0, stream>>>(A, guide);
    gf_stats<<<256, 256, 0, stream>>>(guide, meanI, varI);
    // 3. conv2 prep: zero y1p border, repack w2 into MFMA B-frag order
    border_zero<<<4225, 256, 0, stream>>>(y1p);
    repack_w2<<<800, 256, 0, stream>>>(w2, wpk);
    // 4. conv1 (1x1, 263->256, relu) -> y1p (bf16, padded, pixel-major)
    conv1_gemm<<<dim3(P2 / GP, 256 / GOC), 256, 0, stream>>>(w1, A, b1, y1p, 263);
    // 5. conv2 (5x5 MFMA) -> A ([oc][p] fp32)
    conv5x5_mfma<<<dim3(16, 32, 2), 256, 0, stream>>>(y1p, wpk, b2, A);
    // 6. guided filter : A -> B
    gf_fused<<<dim3(16, 16, 256), 256, 0, stream>>>(A, guide, meanI, varI, B);
    // 7. conv3 (1x1, 256->256, relu) -> out+P2 (feat_2x)
    gemm_bias_relu<<<dim3(P2 / GP, 256 / GOC), 256, 0, stream>>>(w3, B, b3, out + P2, 256);
    // 8. mask head -> out[0..P2)
    mask_head<<<256, 256, 0, stream>>>(out + P2, wm, bm, out);
}

// Round 4
// 549.222 us; speedup vs baseline: 5.9787x; 1.8301x over previous
//
#include <hip/hip_runtime.h>
#include <hip/hip_bf16.h>
#include <math.h>

// GuidedUpsampleUnitGF — bf16 MFMA for conv1/conv2/conv3; streaming separable guided filter.
// upsample(bf16 chunk-planar) -> guide(fp32) -> gf_stats -> repacks/border ->
// conv1 MFMA -> conv2 MFMA(5x5) -> gf_stream -> transpose -> conv3 MFMA -> mask head.

#define P2 65536            // 256*256 pixels
#define PADW 260            // padded image width/height for conv2 (halo 2)

typedef short  frag8  __attribute__((ext_vector_type(8)));   // 8 bf16 (4 VGPRs)
typedef float  f32x4  __attribute__((ext_vector_type(4)));

__device__ __forceinline__ void load16_lds(const void* gsrc, void* lds) {
    __builtin_amdgcn_global_load_lds((const __attribute__((address_space(1))) void*)gsrc,
                                     (__attribute__((address_space(3))) void*)lds, 16, 0, 0);
}

// bilinear 2x upsample coords (half-pixel centers, edge-clamped {0.25,0.75})
struct BilC { int y0, y1, x0, x1; float wy0, wy1, wx0, wx1; };
__device__ __forceinline__ BilC bil_coords(int oy, int ox) {
    BilC c;
    int m = oy >> 1;
    if ((oy & 1) == 0) { c.y0 = (m > 0) ? m - 1 : 0; c.y1 = m; c.wy0 = 0.25f; }
    else               { c.y0 = m; c.y1 = (m < 127) ? m + 1 : 127; c.wy0 = 0.75f; }
    c.wy1 = 1.0f - c.wy0;
    int n = ox >> 1;
    if ((ox & 1) == 0) { c.x0 = (n > 0) ? n - 1 : 0; c.x1 = n; c.wx0 = 0.25f; }
    else               { c.x0 = n; c.x1 = (n < 127) ? n + 1 : 127; c.wx0 = 0.75f; }
    c.wx1 = 1.0f - c.wx0;
    return c;
}
__device__ __forceinline__ float bil_eval(const float* __restrict__ src, const BilC& c) {
    return c.wy0 * (c.wx0 * src[c.y0 * 128 + c.x0] + c.wx1 * src[c.y0 * 128 + c.x1])
         + c.wy1 * (c.wx0 * src[c.y1 * 128 + c.x0] + c.wx1 * src[c.y1 * 128 + c.x1]);
}

// ---------------------------------------------------------------- upsample -> bf16 chunk-planar x
// xp layout: [36][P2][8] bf16 ; chunk ch holds channels ch*8..ch*8+7 (c>=263 zero)
__global__ void upsample_x(const float* __restrict__ mask, const float* __restrict__ fg,
                           const float* __restrict__ bg, const float* __restrict__ feat,
                           __hip_bfloat16* __restrict__ xp) {
    int p = blockIdx.x * 256 + threadIdx.x;
    int chunk = blockIdx.y;
    union { __hip_bfloat16 h[8]; f32x4 v; } u;
    if (chunk >= 33) {
        f32x4 z = {0.f, 0.f, 0.f, 0.f};
        *(f32x4*)&xp[((size_t)chunk * P2 + p) * 8] = z;
        return;
    }
    BilC bc = bil_coords(p >> 8, p & 255);
#pragma unroll
    for (int j = 0; j < 8; j++) {
        int c = chunk * 8 + j;
        float v = 0.f;
        if (c < 263) {
            const float* src = (c == 0) ? mask
                             : (c < 4)  ? fg + (c - 1) * 16384
                             : (c < 7)  ? bg + (c - 4) * 16384
                             :            feat + (c - 7) * 16384;
            v = bil_eval(src, bc);
        }
        u.h[j] = __float2bfloat16(v);
    }
    *(f32x4*)&xp[((size_t)chunk * P2 + p) * 8] = u.v;
}

// ---------------------------------------------------------------- guide (exact fp32 from fg)
__global__ void guide_make(const float* __restrict__ fg, float* __restrict__ guide) {
    int p = blockIdx.x * 256 + threadIdx.x;
    BilC bc = bil_coords(p >> 8, p & 255);
    float s = bil_eval(fg, bc) + bil_eval(fg + 16384, bc) + bil_eval(fg + 32768, bc);
    guide[p] = s * (128.0f / 3.0f);
}

// ---------------------------------------------------------------- guided filter stats
__global__ void gf_stats(const float* __restrict__ guide, float* __restrict__ meanI,
                         float* __restrict__ varI) {
    int p = blockIdx.x * 256 + threadIdx.x;
    int y = p >> 8, xq = p & 255;
    int y0 = (y - 2 > 0) ? y - 2 : 0, y1 = (y + 2 < 255) ? y + 2 : 255;
    int x0 = (xq - 2 > 0) ? xq - 2 : 0, x1 = (xq + 2 < 255) ? xq + 2 : 255;
    float s = 0.f, ss = 0.f;
    for (int yy = y0; yy <= y1; yy++)
        for (int xx = x0; xx <= x1; xx++) {
            float v = guide[yy * 256 + xx];
            s += v; ss += v * v;
        }
    float inv = 1.0f / (float)((y1 - y0 + 1) * (x1 - x0 + 1));
    float m = s * inv;
    meanI[p] = m;
    varI[p] = ss * inv - m * m;
}

// ---------------------------------------------------------------- zero padded border of y1p
__global__ void border_zero(__hip_bfloat16* __restrict__ y1p) {
    int idx = blockIdx.x * 256 + threadIdx.x;
    int p = idx >> 4;
    if (p >= PADW * PADW) return;
    int py = p / PADW, px = p - py * PADW;
    if (py >= 2 && py < 258 && px >= 2 && px < 258) return;
    f32x4 z = {0.f, 0.f, 0.f, 0.f};
    f32x4* dst = (f32x4*)&y1p[(size_t)p * 256 + (idx & 15) * 16];
    dst[0] = z; dst[1] = z;
}

// ---------------------------------------------------------------- repack 1x1 weights -> B-frag order
// dst[kt][nbg16][lane64][8] : value j = W[oc = nbg*16+(lane&15)][ic = kt*32+(lane>>4)*8+j], 0 if ic>=K
__global__ void repack_1x1(const float* __restrict__ W, __hip_bfloat16* __restrict__ dst,
                           int K, int KT) {
    int idx = blockIdx.x * 256 + threadIdx.x;
    if (idx >= KT * 16 * 64) return;
    int lane = idx & 63;
    int nbg = (idx >> 6) & 15;
    int kt = idx >> 10;
    int oc = nbg * 16 + (lane & 15);
    int ic0 = kt * 32 + (lane >> 4) * 8;
    union { __hip_bfloat16 h[8]; f32x4 v; } u;
#pragma unroll
    for (int j = 0; j < 8; j++) {
        int ic = ic0 + j;
        u.h[j] = (ic < K) ? __float2bfloat16(W[(size_t)oc * K + ic]) : __float2bfloat16(0.f);
    }
    *(f32x4*)&dst[(size_t)idx * 8] = u.v;
}

// ---------------------------------------------------------------- repack w2 -> MFMA B-frag order
__global__ void repack_w2(const float* __restrict__ w2, __hip_bfloat16* __restrict__ wpk) {
    int idx = blockIdx.x * 256 + threadIdx.x;        // 25*8*16*64 = 204800
    int lane = idx & 63;
    int nb = (idx >> 6) & 15;
    int kt = (idx >> 10) & 7;
    int t  = idx >> 13;
    int oc = nb * 16 + (lane & 15);
    int ic0 = kt * 32 + (lane >> 4) * 8;
    union { __hip_bfloat16 h[8]; f32x4 v; } u;
#pragma unroll
    for (int j = 0; j < 8; j++)
        u.h[j] = __float2bfloat16(w2[(oc * 256 + ic0 + j) * 25 + t]);
    *(f32x4*)&wpk[(size_t)idx * 8] = u.v;
}

// ---------------------------------------------------------------- generic 1x1 MFMA GEMM
// A: xch [KT*4][P2][8] bf16 chunk-planar; B: wpk [KT][16][64][8].
// block: 128 px x 128 oc; grid (512, 2). MODE 0: bf16 padded NHWC (+relu) -> y1p.
// MODE 1: fp32 planar (+relu) -> out.
template<int MODE>
__global__ __launch_bounds__(256) void mfma_1x1(const __hip_bfloat16* __restrict__ xch,
                                                const __hip_bfloat16* __restrict__ wpk,
                                                const float* __restrict__ bias,
                                                void* __restrict__ outp, int KT) {
    __shared__ __align__(16) __hip_bfloat16 Asm[2][128 * 32];
    __shared__ __align__(16) __hip_bfloat16 Bsm[2][8 * 64 * 8];
    const int tid = threadIdx.x;
    const int wave = tid >> 6, lane = tid & 63;
    const int q = lane >> 4, m16 = lane & 15;
    const int wm = wave & 1, wn = wave >> 1;
    const int pb = blockIdx.x * 128, oh = blockIdx.y;

    f32x4 acc[4][4] = {};

    auto stA = [&](int kt, int buf) {
#pragma unroll
        for (int it = 0; it < 2; it++) {
            int chb = it * 256 + wave * 64;
            int ch = chb + lane;
            int px = ch >> 2, oct = ch & 3;
            const __hip_bfloat16* src = xch + ((size_t)(kt * 4 + oct) * P2 + pb + px) * 8;
            load16_lds(src, &Asm[buf][chb * 8]);
        }
    };
    auto stB = [&](int kt, int buf) {
#pragma unroll
        for (int it = 0; it < 2; it++) {
            int chb = it * 256 + wave * 64;
            int ch = chb + lane;
            int nb = ch >> 6, l = ch & 63;
            const __hip_bfloat16* src = wpk + (((size_t)kt * 16 + oh * 8 + nb) * 64 + l) * 8;
            load16_lds(src, &Bsm[buf][chb * 8]);
        }
    };
    stA(0, 0); stB(0, 0);
    int buf = 0;
    for (int kt = 0; kt < KT; kt++) {
        __syncthreads();
        if (kt + 1 < KT) { stA(kt + 1, buf ^ 1); stB(kt + 1, buf ^ 1); }
        frag8 a[4], b[4];
#pragma unroll
        for (int i = 0; i < 4; i++)
            a[i] = *(const frag8*)&Asm[buf][((wm * 4 + i) * 16 + m16) * 32 + q * 8];
#pragma unroll
        for (int j = 0; j < 4; j++)
            b[j] = *(const frag8*)&Bsm[buf][((wn * 4 + j) * 64 + lane) * 8];
#pragma unroll
        for (int i = 0; i < 4; i++)
#pragma unroll
            for (int j = 0; j < 4; j++)
                acc[i][j] = __builtin_amdgcn_mfma_f32_16x16x32_bf16(a[i], b[j], acc[i][j], 0, 0, 0);
        buf ^= 1;
    }
    if (MODE == 0) {
        __hip_bfloat16* y1p = (__hip_bfloat16*)outp;
#pragma unroll
        for (int j = 0; j < 4; j++) {
            int oc = oh * 128 + (wn * 4 + j) * 16 + m16;
            float bj = bias[oc];
#pragma unroll
            for (int i = 0; i < 4; i++) {
                f32x4 v = acc[i][j];
#pragma unroll
                for (int e = 0; e < 4; e++) {
                    int pix = pb + (wm * 4 + i) * 16 + q * 4 + e;
                    int py = pix >> 8, px = pix & 255;
                    float tv = v[e] + bj;
                    y1p[((size_t)(py + 2) * PADW + px + 2) * 256 + oc] =
                        __float2bfloat16(tv > 0.f ? tv : 0.f);
                }
            }
        }
    } else {
        float* out = (float*)outp;
#pragma unroll
        for (int j = 0; j < 4; j++) {
            int oc = oh * 128 + (wn * 4 + j) * 16 + m16;
            float bj = bias[oc];
#pragma unroll
            for (int i = 0; i < 4; i++) {
                f32x4 v = acc[i][j];
#pragma unroll
                for (int e = 0; e < 4; e++) { float tv = v[e] + bj; v[e] = tv > 0.f ? tv : 0.f; }
                *(f32x4*)&out[(size_t)oc * P2 + pb + (wm * 4 + i) * 16 + q * 4] = v;
            }
        }
    }
}

// ---------------------------------------------------------------- conv2: 5x5 MFMA implicit GEMM (unchanged)
__global__ __launch_bounds__(256) void conv5x5_mfma(const __hip_bfloat16* __restrict__ y1p,
                                                    const __hip_bfloat16* __restrict__ wpk,
                                                    const float* __restrict__ bias,
                                                    float* __restrict__ out) {
    __shared__ __align__(16) __hip_bfloat16 Asm[2][12 * 20 * 32];
    __shared__ __align__(16) __hip_bfloat16 Bsm[2][8 * 64 * 8];
    const int tid = threadIdx.x;
    const int wave = tid >> 6;
    const int lane = tid & 63;
    const int q = lane >> 4;
    const int m16 = lane & 15;
    const int wm = wave & 1;
    const int wn = wave >> 1;
    const int bx = blockIdx.x, by = blockIdx.y, oh = blockIdx.z;

    f32x4 acc[4][4] = {};

    auto stageA = [&](int ict, int buf) {
#pragma unroll
        for (int it = 0; it < 3; it++) {
            int chb = it * 256 + wave * 64;
            int ch = chb + lane;
            int oct = ch & 3, pl = ch >> 2;
            int pc = pl % 20, pr = pl / 20;
            const __hip_bfloat16* src =
                y1p + (size_t)((by * 8 + pr) * PADW + bx * 16 + pc) * 256 + ict * 32 + oct * 8;
            load16_lds(src, &Asm[buf][chb * 8]);
        }
        if (wave < 3) {
            int chb = 768 + wave * 64;
            int ch = chb + lane;
            int oct = ch & 3, pl = ch >> 2;
            int pc = pl % 20, pr = pl / 20;
            const __hip_bfloat16* src =
                y1p + (size_t)((by * 8 + pr) * PADW + bx * 16 + pc) * 256 + ict * 32 + oct * 8;
            load16_lds(src, &Asm[buf][chb * 8]);
        }
    };
    auto stageB = [&](int s, int buf) {
        int ict = s / 25, tap = s - ict * 25;
        const __hip_bfloat16* base = wpk + (size_t)((tap * 8 + ict) * 16 + oh * 8) * 512;
#pragma unroll
        for (int it = 0; it < 2; it++) {
            int chb = it * 256 + wave * 64;
            load16_lds(base + (chb + lane) * 8, &Bsm[buf][chb * 8]);
        }
    };

    stageA(0, 0);
    stageB(0, 0);
    int abuf = 0, bbuf = 0;
    for (int s = 0; s < 200; s++) {
        __syncthreads();
        int ict = s / 25, tap = s - ict * 25;
        if (s + 1 < 200) stageB(s + 1, bbuf ^ 1);
        if (tap == 24 && ict < 7) stageA(ict + 1, abuf ^ 1);
        int dy = tap / 5, dx = tap - dy * 5;
        frag8 a[4], b[4];
#pragma unroll
        for (int i = 0; i < 4; i++) {
            int r = wm * 4 + i;
            a[i] = *(const frag8*)&Asm[abuf][((r + dy) * 20 + m16 + dx) * 32 + q * 8];
        }
#pragma unroll
        for (int j = 0; j < 4; j++)
            b[j] = *(const frag8*)&Bsm[bbuf][((wn * 4 + j) * 64 + lane) * 8];
#pragma unroll
        for (int i = 0; i < 4; i++)
#pragma unroll
            for (int j = 0; j < 4; j++)
                acc[i][j] = __builtin_amdgcn_mfma_f32_16x16x32_bf16(a[i], b[j], acc[i][j], 0, 0, 0);
        bbuf ^= 1;
        if (tap == 24) abuf ^= 1;
    }

#pragma unroll
    for (int j = 0; j < 4; j++) {
        int oc = oh * 128 + (wn * 4 + j) * 16 + m16;
        float bj = bias[oc];
#pragma unroll
        for (int i = 0; i < 4; i++) {
            int r = wm * 4 + i;
            f32x4 v = acc[i][j];
#pragma unroll
            for (int e = 0; e < 4; e++) {
                float t = v[e] + bj;
                v[e] = (t > 0.f) ? t : 0.f;
            }
            *(f32x4*)&out[(size_t)oc * P2 + (by * 8 + r) * 256 + bx * 16 + q * 4] = v;
        }
    }
}

// ---------------------------------------------------------------- guided filter: streaming separable
// block = (band bx: 64 rows, channel by). thread t = column x. fp32 internal, bf16 [c][p] out.
__global__ __launch_bounds__(256) void gf_stream(const float* __restrict__ p,
                                                 const float* __restrict__ guide,
                                                 const float* __restrict__ meanI,
                                                 const float* __restrict__ varI,
                                                 __hip_bfloat16* __restrict__ filt) {
    __shared__ float Prow[260], IProw[260], Arow[260], Brow[260];
    const int t = threadIdx.x;
    const int c = blockIdx.y;
    const int Y0 = blockIdx.x * 64;
    const float* pc = p + (size_t)c * P2;
    if (t < 4) {
        int e = (t < 2) ? t : 256 + t;
        Prow[e] = 0.f; IProw[e] = 0.f; Arow[e] = 0.f; Brow[e] = 0.f;
    }
    int xlo = (t - 2 > 0) ? t - 2 : 0, xhi = (t + 2 < 255) ? t + 2 : 255;
    const float cxr = 1.0f / (float)(xhi - xlo + 1);
    float hp[5] = {0, 0, 0, 0, 0}, hip[5] = {0, 0, 0, 0, 0};
    float ha[5] = {0, 0, 0, 0, 0}, hb[5] = {0, 0, 0, 0, 0};
    float vp = 0.f, vip = 0.f, va = 0.f, vb = 0.f;
    __syncthreads();
    for (int s = 0; s < 72; s++) {
        int yL = Y0 - 4 + s;
        bool okL = ((unsigned)yL < 256u);
        if (okL) {
            float pv = pc[yL * 256 + t];
            Prow[t + 2] = pv;
            IProw[t + 2] = guide[yL * 256 + t] * pv;
        }
        __syncthreads();
        float hpn = 0.f, hipn = 0.f;
        if (okL) {
            hpn  = Prow[t] + Prow[t + 1] + Prow[t + 2] + Prow[t + 3] + Prow[t + 4];
            hipn = IProw[t] + IProw[t + 1] + IProw[t + 2] + IProw[t + 3] + IProw[t + 4];
        }
        vp += hpn - hp[0];  vip += hipn - hip[0];
        hp[0] = hp[1]; hp[1] = hp[2]; hp[2] = hp[3]; hp[3] = hp[4]; hp[4] = hpn;
        hip[0] = hip[1]; hip[1] = hip[2]; hip[2] = hip[3]; hip[3] = hip[4]; hip[4] = hipn;
        int yA = yL - 2;
        float aV = 0.f, bV = 0.f;
        if ((unsigned)yA < 256u && yA >= Y0 - 2) {
            int ylo = (yA - 2 > 0) ? yA - 2 : 0, yhi = (yA + 2 < 255) ? yA + 2 : 255;
            float inv1 = cxr / (float)(yhi - ylo + 1);
            float mI = meanI[yA * 256 + t], vI = varI[yA * 256 + t];
            float mp = vp * inv1, mip = vip * inv1;
            float cov = mip - mI * mp;
            aV = cov / (vI + 0.01f);
            bV = mp - aV * mI;
        }
        Arow[t + 2] = aV;
        Brow[t + 2] = bV;
        __syncthreads();
        float han = Arow[t] + Arow[t + 1] + Arow[t + 2] + Arow[t + 3] + Arow[t + 4];
        float hbn = Brow[t] + Brow[t + 1] + Brow[t + 2] + Brow[t + 3] + Brow[t + 4];
        va += han - ha[0];  vb += hbn - hb[0];
        ha[0] = ha[1]; ha[1] = ha[2]; ha[2] = ha[3]; ha[3] = ha[4]; ha[4] = han;
        hb[0] = hb[1]; hb[1] = hb[2]; hb[2] = hb[3]; hb[3] = hb[4]; hb[4] = hbn;
        int yo = yL - 4;
        if (yo >= Y0 && yo < Y0 + 64 && (unsigned)yo < 256u) {
            int ylo = (yo - 2 > 0) ? yo - 2 : 0, yhi = (yo + 2 < 255) ? yo + 2 : 255;
            float inv2 = cxr / (float)(yhi - ylo + 1);
            float I = guide[yo * 256 + t];
            filt[(size_t)c * P2 + yo * 256 + t] = __float2bfloat16((va * I + vb) * inv2);
        }
    }
}

// ---------------------------------------------------------------- transpose bf16 [c][p] -> chunk-planar [32][P2][8]
__global__ void transpose_cp(const __hip_bfloat16* __restrict__ filt,
                             __hip_bfloat16* __restrict__ filtp) {
    __shared__ __hip_bfloat16 T[8][1024];
    int tid = threadIdx.x;
    int p0 = blockIdx.x * 1024;
    int cg = blockIdx.y;
    for (int i = tid; i < 8192; i += 256) {
        int r = i >> 10, pl = i & 1023;
        T[r][pl] = filt[(size_t)(cg * 8 + r) * P2 + p0 + pl];
    }
    __syncthreads();
    for (int pl = tid; pl < 1024; pl += 256) {
        union { __hip_bfloat16 h[8]; f32x4 v; } u;
#pragma unroll
        for (int j = 0; j < 8; j++) u.h[j] = T[j][pl];
        *(f32x4*)&filtp[((size_t)cg * P2 + p0 + pl) * 8] = u.v;
    }
}

// ---------------------------------------------------------------- mask head (1x1 conv -> sigmoid)
__global__ void mask_head(const float* __restrict__ feat, const float* __restrict__ wm,
                          const float* __restrict__ bm, float* __restrict__ out) {
    int p = blockIdx.x * 256 + threadIdx.x;
    float acc = bm[0];
    for (int c = 0; c < 256; c++) acc += wm[c] * feat[(size_t)c * P2 + p];
    out[p] = 1.0f / (1.0f + expf(-acc));
}

// ---------------------------------------------------------------- launch
extern "C" void kernel_launch(void* const* d_in, const int* in_sizes, int n_in,
                              void* d_out, int out_size, void* d_ws, size_t ws_size,
                              hipStream_t stream) {
    const float* fg   = (const float*)d_in[0];
    const float* bg   = (const float*)d_in[1];
    const float* mask = (const float*)d_in[2];
    const float* feat = (const float*)d_in[3];
    const float* w1   = (const float*)d_in[4];
    const float* b1   = (const float*)d_in[5];
    const float* w2   = (const float*)d_in[6];
    const float* b2   = (const float*)d_in[7];
    const float* w3   = (const float*)d_in[8];
    const float* b3   = (const float*)d_in[9];
    const float* wm   = (const float*)d_in[10];
    const float* bm   = (const float*)d_in[11];
    float* out = (float*)d_out;
    char* w8 = (char*)d_ws;

    float* pbuf = (float*)w8;                                    // 67,108,864 B (conv2 out)
    __hip_bfloat16* xp    = (__hip_bfloat16*)(w8 + 67108864);    // 37,748,736 B [36][P2][8]
    __hip_bfloat16* filt  = (__hip_bfloat16*)(w8 + 67108864);    // alias xp (xp dead after conv1)
    __hip_bfloat16* filtp = (__hip_bfloat16*)w8;                 // alias pbuf (dead after gf)
    __hip_bfloat16* y1p   = (__hip_bfloat16*)(w8 + 104857600);   // 34,611,200 B
    __hip_bfloat16* wpk2  = (__hip_bfloat16*)(w8 + 139468800);   // 3,276,800 B
    __hip_bfloat16* wpk1  = (__hip_bfloat16*)(w8 + 142745600);   // 147,456 B
    __hip_bfloat16* wpk3  = (__hip_bfloat16*)(w8 + 142893056);   // 131,072 B
    float* guide = (float*)(w8 + 143024128);
    float* meanI = guide + P2;
    float* varI  = meanI + P2;

    // 1. upsample + concat -> xp (bf16 chunk-planar, K padded to 288)
    upsample_x<<<dim3(256, 36), 256, 0, stream>>>(mask, fg, bg, feat, xp);
    // 2. guide (exact fp32) + stats
    guide_make<<<256, 256, 0, stream>>>(fg, guide);
    gf_stats<<<256, 256, 0, stream>>>(guide, meanI, varI);
    // 3. prep: y1p border, weight repacks
    border_zero<<<4225, 256, 0, stream>>>(y1p);
    repack_w2<<<800, 256, 0, stream>>>(w2, wpk2);
    repack_1x1<<<36, 256, 0, stream>>>(w1, wpk1, 263, 9);
    repack_1x1<<<32, 256, 0, stream>>>(w3, wpk3, 256, 8);
    // 4. conv1 (1x1 MFMA, 288-pad K) -> y1p
    mfma_1x1<0><<<dim3(512, 2), 256, 0, stream>>>(xp, wpk1, b1, y1p, 9);
    // 5. conv2 (5x5 MFMA) -> pbuf
    conv5x5_mfma<<<dim3(16, 32, 2), 256, 0, stream>>>(y1p, wpk2, b2, pbuf);
    // 6. guided filter (streaming separable) -> filt (bf16 [c][p])
    gf_stream<<<dim3(4, 256), 256, 0, stream>>>(pbuf, guide, meanI, varI, filt);
    // 7. transpose -> filtp (chunk-planar)
    transpose_cp<<<dim3(64, 32), 256, 0, stream>>>(filt, filtp);
    // 8. conv3 (1x1 MFMA) -> out+P2 (fp32 planar, relu)
    mfma_1x1<1><<<dim3(512, 2), 256, 0, stream>>>(filtp, wpk3, b3, out + P2, 8);
    // 9. mask head -> out[0..P2)
    mask_head<<<256, 256, 0, stream>>>(out + P2, wm, bm, out);
}

// Round 5
// 459.400 us; speedup vs baseline: 7.1477x; 1.1955x over previous
//
#include <hip/hip_runtime.h>
#include <hip/hip_bf16.h>
#include <math.h>

// GuidedUpsampleUnitGF — bf16 MFMA for conv1/conv2/conv3; streaming separable guided filter.
// R5: conv2 restructured — B weights stream global->register (no LDS, no per-step barrier),
// 2 waves/block each 4Mx8N, A-patch double-buffered with barrier only at ic-tile flips.

#define P2 65536            // 256*256 pixels
#define PADW 260            // padded image width/height for conv2 (halo 2)

typedef short  frag8  __attribute__((ext_vector_type(8)));   // 8 bf16 (4 VGPRs)
typedef float  f32x4  __attribute__((ext_vector_type(4)));

__device__ __forceinline__ void load16_lds(const void* gsrc, void* lds) {
    __builtin_amdgcn_global_load_lds((const __attribute__((address_space(1))) void*)gsrc,
                                     (__attribute__((address_space(3))) void*)lds, 16, 0, 0);
}

// bilinear 2x upsample coords (half-pixel centers, edge-clamped {0.25,0.75})
struct BilC { int y0, y1, x0, x1; float wy0, wy1, wx0, wx1; };
__device__ __forceinline__ BilC bil_coords(int oy, int ox) {
    BilC c;
    int m = oy >> 1;
    if ((oy & 1) == 0) { c.y0 = (m > 0) ? m - 1 : 0; c.y1 = m; c.wy0 = 0.25f; }
    else               { c.y0 = m; c.y1 = (m < 127) ? m + 1 : 127; c.wy0 = 0.75f; }
    c.wy1 = 1.0f - c.wy0;
    int n = ox >> 1;
    if ((ox & 1) == 0) { c.x0 = (n > 0) ? n - 1 : 0; c.x1 = n; c.wx0 = 0.25f; }
    else               { c.x0 = n; c.x1 = (n < 127) ? n + 1 : 127; c.wx0 = 0.75f; }
    c.wx1 = 1.0f - c.wx0;
    return c;
}
__device__ __forceinline__ float bil_eval(const float* __restrict__ src, const BilC& c) {
    return c.wy0 * (c.wx0 * src[c.y0 * 128 + c.x0] + c.wx1 * src[c.y0 * 128 + c.x1])
         + c.wy1 * (c.wx0 * src[c.y1 * 128 + c.x0] + c.wx1 * src[c.y1 * 128 + c.x1]);
}

// ---------------------------------------------------------------- upsample -> bf16 chunk-planar x
// xp layout: [36][P2][8] bf16 ; chunk ch holds channels ch*8..ch*8+7 (c>=263 zero)
__global__ void upsample_x(const float* __restrict__ mask, const float* __restrict__ fg,
                           const float* __restrict__ bg, const float* __restrict__ feat,
                           __hip_bfloat16* __restrict__ xp) {
    int p = blockIdx.x * 256 + threadIdx.x;
    int chunk = blockIdx.y;
    union { __hip_bfloat16 h[8]; f32x4 v; } u;
    if (chunk >= 33) {
        f32x4 z = {0.f, 0.f, 0.f, 0.f};
        *(f32x4*)&xp[((size_t)chunk * P2 + p) * 8] = z;
        return;
    }
    BilC bc = bil_coords(p >> 8, p & 255);
#pragma unroll
    for (int j = 0; j < 8; j++) {
        int c = chunk * 8 + j;
        float v = 0.f;
        if (c < 263) {
            const float* src = (c == 0) ? mask
                             : (c < 4)  ? fg + (c - 1) * 16384
                             : (c < 7)  ? bg + (c - 4) * 16384
                             :            feat + (c - 7) * 16384;
            v = bil_eval(src, bc);
        }
        u.h[j] = __float2bfloat16(v);
    }
    *(f32x4*)&xp[((size_t)chunk * P2 + p) * 8] = u.v;
}

// ---------------------------------------------------------------- guide (exact fp32 from fg)
__global__ void guide_make(const float* __restrict__ fg, float* __restrict__ guide) {
    int p = blockIdx.x * 256 + threadIdx.x;
    BilC bc = bil_coords(p >> 8, p & 255);
    float s = bil_eval(fg, bc) + bil_eval(fg + 16384, bc) + bil_eval(fg + 32768, bc);
    guide[p] = s * (128.0f / 3.0f);
}

// ---------------------------------------------------------------- guided filter stats
__global__ void gf_stats(const float* __restrict__ guide, float* __restrict__ meanI,
                         float* __restrict__ varI) {
    int p = blockIdx.x * 256 + threadIdx.x;
    int y = p >> 8, xq = p & 255;
    int y0 = (y - 2 > 0) ? y - 2 : 0, y1 = (y + 2 < 255) ? y + 2 : 255;
    int x0 = (xq - 2 > 0) ? xq - 2 : 0, x1 = (xq + 2 < 255) ? xq + 2 : 255;
    float s = 0.f, ss = 0.f;
    for (int yy = y0; yy <= y1; yy++)
        for (int xx = x0; xx <= x1; xx++) {
            float v = guide[yy * 256 + xx];
            s += v; ss += v * v;
        }
    float inv = 1.0f / (float)((y1 - y0 + 1) * (x1 - x0 + 1));
    float m = s * inv;
    meanI[p] = m;
    varI[p] = ss * inv - m * m;
}

// ---------------------------------------------------------------- zero padded border of y1p
__global__ void border_zero(__hip_bfloat16* __restrict__ y1p) {
    int idx = blockIdx.x * 256 + threadIdx.x;
    int p = idx >> 4;
    if (p >= PADW * PADW) return;
    int py = p / PADW, px = p - py * PADW;
    if (py >= 2 && py < 258 && px >= 2 && px < 258) return;
    f32x4 z = {0.f, 0.f, 0.f, 0.f};
    f32x4* dst = (f32x4*)&y1p[(size_t)p * 256 + (idx & 15) * 16];
    dst[0] = z; dst[1] = z;
}

// ---------------------------------------------------------------- repack 1x1 weights -> B-frag order
__global__ void repack_1x1(const float* __restrict__ W, __hip_bfloat16* __restrict__ dst,
                           int K, int KT) {
    int idx = blockIdx.x * 256 + threadIdx.x;
    if (idx >= KT * 16 * 64) return;
    int lane = idx & 63;
    int nbg = (idx >> 6) & 15;
    int kt = idx >> 10;
    int oc = nbg * 16 + (lane & 15);
    int ic0 = kt * 32 + (lane >> 4) * 8;
    union { __hip_bfloat16 h[8]; f32x4 v; } u;
#pragma unroll
    for (int j = 0; j < 8; j++) {
        int ic = ic0 + j;
        u.h[j] = (ic < K) ? __float2bfloat16(W[(size_t)oc * K + ic]) : __float2bfloat16(0.f);
    }
    *(f32x4*)&dst[(size_t)idx * 8] = u.v;
}

// ---------------------------------------------------------------- repack w2 -> MFMA B-frag order
__global__ void repack_w2(const float* __restrict__ w2, __hip_bfloat16* __restrict__ wpk) {
    int idx = blockIdx.x * 256 + threadIdx.x;        // 25*8*16*64 = 204800
    int lane = idx & 63;
    int nb = (idx >> 6) & 15;
    int kt = (idx >> 10) & 7;
    int t  = idx >> 13;
    int oc = nb * 16 + (lane & 15);
    int ic0 = kt * 32 + (lane >> 4) * 8;
    union { __hip_bfloat16 h[8]; f32x4 v; } u;
#pragma unroll
    for (int j = 0; j < 8; j++)
        u.h[j] = __float2bfloat16(w2[(oc * 256 + ic0 + j) * 25 + t]);
    *(f32x4*)&wpk[(size_t)idx * 8] = u.v;
}

// ---------------------------------------------------------------- generic 1x1 MFMA GEMM (unchanged)
template<int MODE>
__global__ __launch_bounds__(256) void mfma_1x1(const __hip_bfloat16* __restrict__ xch,
                                                const __hip_bfloat16* __restrict__ wpk,
                                                const float* __restrict__ bias,
                                                void* __restrict__ outp, int KT) {
    __shared__ __align__(16) __hip_bfloat16 Asm[2][128 * 32];
    __shared__ __align__(16) __hip_bfloat16 Bsm[2][8 * 64 * 8];
    const int tid = threadIdx.x;
    const int wave = tid >> 6, lane = tid & 63;
    const int q = lane >> 4, m16 = lane & 15;
    const int wm = wave & 1, wn = wave >> 1;
    const int pb = blockIdx.x * 128, oh = blockIdx.y;

    f32x4 acc[4][4] = {};

    auto stA = [&](int kt, int buf) {
#pragma unroll
        for (int it = 0; it < 2; it++) {
            int chb = it * 256 + wave * 64;
            int ch = chb + lane;
            int px = ch >> 2, oct = ch & 3;
            const __hip_bfloat16* src = xch + ((size_t)(kt * 4 + oct) * P2 + pb + px) * 8;
            load16_lds(src, &Asm[buf][chb * 8]);
        }
    };
    auto stB = [&](int kt, int buf) {
#pragma unroll
        for (int it = 0; it < 2; it++) {
            int chb = it * 256 + wave * 64;
            int ch = chb + lane;
            int nb = ch >> 6, l = ch & 63;
            const __hip_bfloat16* src = wpk + (((size_t)kt * 16 + oh * 8 + nb) * 64 + l) * 8;
            load16_lds(src, &Bsm[buf][chb * 8]);
        }
    };
    stA(0, 0); stB(0, 0);
    int buf = 0;
    for (int kt = 0; kt < KT; kt++) {
        __syncthreads();
        if (kt + 1 < KT) { stA(kt + 1, buf ^ 1); stB(kt + 1, buf ^ 1); }
        frag8 a[4], b[4];
#pragma unroll
        for (int i = 0; i < 4; i++)
            a[i] = *(const frag8*)&Asm[buf][((wm * 4 + i) * 16 + m16) * 32 + q * 8];
#pragma unroll
        for (int j = 0; j < 4; j++)
            b[j] = *(const frag8*)&Bsm[buf][((wn * 4 + j) * 64 + lane) * 8];
#pragma unroll
        for (int i = 0; i < 4; i++)
#pragma unroll
            for (int j = 0; j < 4; j++)
                acc[i][j] = __builtin_amdgcn_mfma_f32_16x16x32_bf16(a[i], b[j], acc[i][j], 0, 0, 0);
        buf ^= 1;
    }
    if (MODE == 0) {
        __hip_bfloat16* y1p = (__hip_bfloat16*)outp;
#pragma unroll
        for (int j = 0; j < 4; j++) {
            int oc = oh * 128 + (wn * 4 + j) * 16 + m16;
            float bj = bias[oc];
#pragma unroll
            for (int i = 0; i < 4; i++) {
                f32x4 v = acc[i][j];
#pragma unroll
                for (int e = 0; e < 4; e++) {
                    int pix = pb + (wm * 4 + i) * 16 + q * 4 + e;
                    int py = pix >> 8, px = pix & 255;
                    float tv = v[e] + bj;
                    y1p[((size_t)(py + 2) * PADW + px + 2) * 256 + oc] =
                        __float2bfloat16(tv > 0.f ? tv : 0.f);
                }
            }
        }
    } else {
        float* out = (float*)outp;
#pragma unroll
        for (int j = 0; j < 4; j++) {
            int oc = oh * 128 + (wn * 4 + j) * 16 + m16;
            float bj = bias[oc];
#pragma unroll
            for (int i = 0; i < 4; i++) {
                f32x4 v = acc[i][j];
#pragma unroll
                for (int e = 0; e < 4; e++) { float tv = v[e] + bj; v[e] = tv > 0.f ? tv : 0.f; }
                *(f32x4*)&out[(size_t)oc * P2 + pb + (wm * 4 + i) * 16 + q * 4] = v;
            }
        }
    }
}

// ---------------------------------------------------------------- conv2: 5x5 MFMA implicit GEMM, R5
// block: 128 threads = 2 waves; each wave 4M (16px strips) x 8N (128 oc).
// A: LDS double-buffer (global_load_lds), barrier only at ic-tile flip (8 total).
// B: global->register, one-step ping-pong prefetch (L1/L2-resident weights).
__global__ __launch_bounds__(128, 2) void conv5x5_mfma(const __hip_bfloat16* __restrict__ y1p,
                                                       const __hip_bfloat16* __restrict__ wpk,
                                                       const float* __restrict__ bias,
                                                       float* __restrict__ out) {
    __shared__ __align__(16) __hip_bfloat16 Asm[2][12 * 20 * 32];  // 2 x 15360 B
    const int tid = threadIdx.x;
    const int wave = tid >> 6;
    const int lane = tid & 63;
    const int q = lane >> 4;
    const int m16 = lane & 15;
    const int bx = blockIdx.x, by = blockIdx.y, oh = blockIdx.z;

    f32x4 acc[4][8] = {};

    auto stageA = [&](int ict, int buf) {
        // 960 chunks of 16B in 15 groups of 64; lds base wave-uniform, src per-lane
#pragma unroll
        for (int g = 0; g < 8; g++) {
            int grp = g * 2 + wave;
            if (grp >= 15) break;
            int chb = grp * 64;
            int ch = chb + lane;
            int oct = ch & 3, pl = ch >> 2;
            int pc = pl % 20, pr = pl / 20;
            const __hip_bfloat16* src =
                y1p + (size_t)((by * 8 + pr) * PADW + bx * 16 + pc) * 256 + ict * 32 + oct * 8;
            load16_lds(src, &Asm[buf][chb * 8]);
        }
    };
    auto loadB = [&](int s, frag8* dst) {
        int ict = s / 25, tap = s - ict * 25;
        const __hip_bfloat16* base =
            wpk + ((size_t)((tap * 8 + ict) * 16 + oh * 8) * 64 + lane) * 8;
#pragma unroll
        for (int j = 0; j < 8; j++)
            dst[j] = *(const frag8*)(base + (size_t)j * 512);
    };

    frag8 bA[8], bB[8];
    stageA(0, 0);
    loadB(0, bA);
    int abuf = 0;

    auto step = [&](int s, frag8* bcur, frag8* bnxt) {
        int ict = s / 25, tap = s - ict * 25;
        if (tap == 0) __syncthreads();               // A buffer ready (vmcnt drained + barrier)
        if (s + 1 < 200) loadB(s + 1, bnxt);         // register prefetch, no barrier
        if (tap == 24 && ict < 7) stageA(ict + 1, abuf ^ 1);
        int dy = tap / 5, dx = tap - dy * 5;
        frag8 a[4];
#pragma unroll
        for (int i = 0; i < 4; i++)
            a[i] = *(const frag8*)&Asm[abuf][((wave * 4 + i + dy) * 20 + m16 + dx) * 32 + q * 8];
#pragma unroll
        for (int i = 0; i < 4; i++)
#pragma unroll
            for (int j = 0; j < 8; j++)
                acc[i][j] = __builtin_amdgcn_mfma_f32_16x16x32_bf16(a[i], bcur[j], acc[i][j], 0, 0, 0);
        if (tap == 24) abuf ^= 1;
    };
    for (int s = 0; s < 200; s += 2) { step(s, bA, bB); step(s + 1, bB, bA); }

    // epilogue: C/D col=lane&15 (oc), row=q*4+e (pixel in strip)
#pragma unroll
    for (int j = 0; j < 8; j++) {
        int oc = oh * 128 + j * 16 + m16;
        float bj = bias[oc];
#pragma unroll
        for (int i = 0; i < 4; i++) {
            int r = wave * 4 + i;
            f32x4 v = acc[i][j];
#pragma unroll
            for (int e = 0; e < 4; e++) {
                float t = v[e] + bj;
                v[e] = (t > 0.f) ? t : 0.f;
            }
            *(f32x4*)&out[(size_t)oc * P2 + (by * 8 + r) * 256 + bx * 16 + q * 4] = v;
        }
    }
}

// ---------------------------------------------------------------- guided filter: streaming separable
__global__ __launch_bounds__(256) void gf_stream(const float* __restrict__ p,
                                                 const float* __restrict__ guide,
                                                 const float* __restrict__ meanI,
                                                 const float* __restrict__ varI,
                                                 __hip_bfloat16* __restrict__ filt) {
    __shared__ float Prow[260], IProw[260], Arow[260], Brow[260];
    const int t = threadIdx.x;
    const int c = blockIdx.y;
    const int Y0 = blockIdx.x * 64;
    const float* pc = p + (size_t)c * P2;
    if (t < 4) {
        int e = (t < 2) ? t : 256 + t;
        Prow[e] = 0.f; IProw[e] = 0.f; Arow[e] = 0.f; Brow[e] = 0.f;
    }
    int xlo = (t - 2 > 0) ? t - 2 : 0, xhi = (t + 2 < 255) ? t + 2 : 255;
    const float cxr = 1.0f / (float)(xhi - xlo + 1);
    float hp[5] = {0, 0, 0, 0, 0}, hip[5] = {0, 0, 0, 0, 0};
    float ha[5] = {0, 0, 0, 0, 0}, hb[5] = {0, 0, 0, 0, 0};
    float vp = 0.f, vip = 0.f, va = 0.f, vb = 0.f;
    __syncthreads();
    for (int s = 0; s < 72; s++) {
        int yL = Y0 - 4 + s;
        bool okL = ((unsigned)yL < 256u);
        if (okL) {
            float pv = pc[yL * 256 + t];
            Prow[t + 2] = pv;
            IProw[t + 2] = guide[yL * 256 + t] * pv;
        }
        __syncthreads();
        float hpn = 0.f, hipn = 0.f;
        if (okL) {
            hpn  = Prow[t] + Prow[t + 1] + Prow[t + 2] + Prow[t + 3] + Prow[t + 4];
            hipn = IProw[t] + IProw[t + 1] + IProw[t + 2] + IProw[t + 3] + IProw[t + 4];
        }
        vp += hpn - hp[0];  vip += hipn - hip[0];
        hp[0] = hp[1]; hp[1] = hp[2]; hp[2] = hp[3]; hp[3] = hp[4]; hp[4] = hpn;
        hip[0] = hip[1]; hip[1] = hip[2]; hip[2] = hip[3]; hip[3] = hip[4]; hip[4] = hipn;
        int yA = yL - 2;
        float aV = 0.f, bV = 0.f;
        if ((unsigned)yA < 256u && yA >= Y0 - 2) {
            int ylo = (yA - 2 > 0) ? yA - 2 : 0, yhi = (yA + 2 < 255) ? yA + 2 : 255;
            float inv1 = cxr / (float)(yhi - ylo + 1);
            float mI = meanI[yA * 256 + t], vI = varI[yA * 256 + t];
            float mp = vp * inv1, mip = vip * inv1;
            float cov = mip - mI * mp;
            aV = cov / (vI + 0.01f);
            bV = mp - aV * mI;
        }
        Arow[t + 2] = aV;
        Brow[t + 2] = bV;
        __syncthreads();
        float han = Arow[t] + Arow[t + 1] + Arow[t + 2] + Arow[t + 3] + Arow[t + 4];
        float hbn = Brow[t] + Brow[t + 1] + Brow[t + 2] + Brow[t + 3] + Brow[t + 4];
        va += han - ha[0];  vb += hbn - hb[0];
        ha[0] = ha[1]; ha[1] = ha[2]; ha[2] = ha[3]; ha[3] = ha[4]; ha[4] = han;
        hb[0] = hb[1]; hb[1] = hb[2]; hb[2] = hb[3]; hb[3] = hb[4]; hb[4] = hbn;
        int yo = yL - 4;
        if (yo >= Y0 && yo < Y0 + 64 && (unsigned)yo < 256u) {
            int ylo = (yo - 2 > 0) ? yo - 2 : 0, yhi = (yo + 2 < 255) ? yo + 2 : 255;
            float inv2 = cxr / (float)(yhi - ylo + 1);
            float I = guide[yo * 256 + t];
            filt[(size_t)c * P2 + yo * 256 + t] = __float2bfloat16((va * I + vb) * inv2);
        }
    }
}

// ---------------------------------------------------------------- transpose bf16 [c][p] -> chunk-planar [32][P2][8]
__global__ void transpose_cp(const __hip_bfloat16* __restrict__ filt,
                             __hip_bfloat16* __restrict__ filtp) {
    __shared__ __hip_bfloat16 T[8][1024];
    int tid = threadIdx.x;
    int p0 = blockIdx.x * 1024;
    int cg = blockIdx.y;
    for (int i = tid; i < 8192; i += 256) {
        int r = i >> 10, pl = i & 1023;
        T[r][pl] = filt[(size_t)(cg * 8 + r) * P2 + p0 + pl];
    }
    __syncthreads();
    for (int pl = tid; pl < 1024; pl += 256) {
        union { __hip_bfloat16 h[8]; f32x4 v; } u;
#pragma unroll
        for (int j = 0; j < 8; j++) u.h[j] = T[j][pl];
        *(f32x4*)&filtp[((size_t)cg * P2 + p0 + pl) * 8] = u.v;
    }
}

// ---------------------------------------------------------------- mask head (1x1 conv -> sigmoid)
__global__ void mask_head(const float* __restrict__ feat, const float* __restrict__ wm,
                          const float* __restrict__ bm, float* __restrict__ out) {
    int p = blockIdx.x * 256 + threadIdx.x;
    float acc = bm[0];
    for (int c = 0; c < 256; c++) acc += wm[c] * feat[(size_t)c * P2 + p];
    out[p] = 1.0f / (1.0f + expf(-acc));
}

// ---------------------------------------------------------------- launch
extern "C" void kernel_launch(void* const* d_in, const int* in_sizes, int n_in,
                              void* d_out, int out_size, void* d_ws, size_t ws_size,
                              hipStream_t stream) {
    const float* fg   = (const float*)d_in[0];
    const float* bg   = (const float*)d_in[1];
    const float* mask = (const float*)d_in[2];
    const float* feat = (const float*)d_in[3];
    const float* w1   = (const float*)d_in[4];
    const float* b1   = (const float*)d_in[5];
    const float* w2   = (const float*)d_in[6];
    const float* b2   = (const float*)d_in[7];
    const float* w3   = (const float*)d_in[8];
    const float* b3   = (const float*)d_in[9];
    const float* wm   = (const float*)d_in[10];
    const float* bm   = (const float*)d_in[11];
    float* out = (float*)d_out;
    char* w8 = (char*)d_ws;

    float* pbuf = (float*)w8;                                    // 67,108,864 B (conv2 out)
    __hip_bfloat16* xp    = (__hip_bfloat16*)(w8 + 67108864);    // 37,748,736 B [36][P2][8]
    __hip_bfloat16* filt  = (__hip_bfloat16*)(w8 + 67108864);    // alias xp (xp dead after conv1)
    __hip_bfloat16* filtp = (__hip_bfloat16*)w8;                 // alias pbuf (dead after gf)
    __hip_bfloat16* y1p   = (__hip_bfloat16*)(w8 + 104857600);   // 34,611,200 B
    __hip_bfloat16* wpk2  = (__hip_bfloat16*)(w8 + 139468800);   // 3,276,800 B
    __hip_bfloat16* wpk1  = (__hip_bfloat16*)(w8 + 142745600);   // 147,456 B
    __hip_bfloat16* wpk3  = (__hip_bfloat16*)(w8 + 142893056);   // 131,072 B
    float* guide = (float*)(w8 + 143024128);
    float* meanI = guide + P2;
    float* varI  = meanI + P2;

    // 1. upsample + concat -> xp (bf16 chunk-planar, K padded to 288)
    upsample_x<<<dim3(256, 36), 256, 0, stream>>>(mask, fg, bg, feat, xp);
    // 2. guide (exact fp32) + stats
    guide_make<<<256, 256, 0, stream>>>(fg, guide);
    gf_stats<<<256, 256, 0, stream>>>(guide, meanI, varI);
    // 3. prep: y1p border, weight repacks
    border_zero<<<4225, 256, 0, stream>>>(y1p);
    repack_w2<<<800, 256, 0, stream>>>(w2, wpk2);
    repack_1x1<<<36, 256, 0, stream>>>(w1, wpk1, 263, 9);
    repack_1x1<<<32, 256, 0, stream>>>(w3, wpk3, 256, 8);
    // 4. conv1 (1x1 MFMA, 288-pad K) -> y1p
    mfma_1x1<0><<<dim3(512, 2), 256, 0, stream>>>(xp, wpk1, b1, y1p, 9);
    // 5. conv2 (5x5 MFMA, R5 structure) -> pbuf
    conv5x5_mfma<<<dim3(16, 32, 2), 128, 0, stream>>>(y1p, wpk2, b2, pbuf);
    // 6. guided filter (streaming separable) -> filt (bf16 [c][p])
    gf_stream<<<dim3(4, 256), 256, 0, stream>>>(pbuf, guide, meanI, varI, filt);
    // 7. transpose -> filtp (chunk-planar)
    transpose_cp<<<dim3(64, 32), 256, 0, stream>>>(filt, filtp);
    // 8. conv3 (1x1 MFMA) -> out+P2 (fp32 planar, relu)
    mfma_1x1<1><<<dim3(512, 2), 256, 0, stream>>>(filtp, wpk3, b3, out + P2, 8);
    // 9. mask head -> out[0..P2)
    mask_head<<<256, 256, 0, stream>>>(out + P2, wm, bm, out);
}

// Round 6
// 442.254 us; speedup vs baseline: 7.4248x; 1.0388x over previous
//
#include <hip/hip_runtime.h>
#include <hip/hip_bf16.h>
#include <hip/hip_fp16.h>
#include <math.h>

// GuidedUpsampleUnitGF — R6: tail optimization round.
// conv2 emits fp16 [c][p]; conv1 epilogue restaged through LDS for coalesced stores;
// prep kernels merged; mask head vectorized. conv2 MFMA core structure = R5 (known 179us/54%).

#define P2 65536            // 256*256 pixels
#define PADW 260            // padded image width/height for conv2 (halo 2)

typedef short  frag8  __attribute__((ext_vector_type(8)));   // 8 bf16 (4 VGPRs)
typedef float  f32x4  __attribute__((ext_vector_type(4)));

__device__ __forceinline__ void load16_lds(const void* gsrc, void* lds) {
    __builtin_amdgcn_global_load_lds((const __attribute__((address_space(1))) void*)gsrc,
                                     (__attribute__((address_space(3))) void*)lds, 16, 0, 0);
}

// bilinear 2x upsample coords (half-pixel centers, edge-clamped {0.25,0.75})
struct BilC { int y0, y1, x0, x1; float wy0, wy1, wx0, wx1; };
__device__ __forceinline__ BilC bil_coords(int oy, int ox) {
    BilC c;
    int m = oy >> 1;
    if ((oy & 1) == 0) { c.y0 = (m > 0) ? m - 1 : 0; c.y1 = m; c.wy0 = 0.25f; }
    else               { c.y0 = m; c.y1 = (m < 127) ? m + 1 : 127; c.wy0 = 0.75f; }
    c.wy1 = 1.0f - c.wy0;
    int n = ox >> 1;
    if ((ox & 1) == 0) { c.x0 = (n > 0) ? n - 1 : 0; c.x1 = n; c.wx0 = 0.25f; }
    else               { c.x0 = n; c.x1 = (n < 127) ? n + 1 : 127; c.wx0 = 0.75f; }
    c.wx1 = 1.0f - c.wx0;
    return c;
}
__device__ __forceinline__ float bil_eval(const float* __restrict__ src, const BilC& c) {
    return c.wy0 * (c.wx0 * src[c.y0 * 128 + c.x0] + c.wx1 * src[c.y0 * 128 + c.x1])
         + c.wy1 * (c.wx0 * src[c.y1 * 128 + c.x0] + c.wx1 * src[c.y1 * 128 + c.x1]);
}

// ---------------------------------------------------------------- upsample -> bf16 chunk-planar x
__global__ void upsample_x(const float* __restrict__ mask, const float* __restrict__ fg,
                           const float* __restrict__ bg, const float* __restrict__ feat,
                           __hip_bfloat16* __restrict__ xp) {
    int p = blockIdx.x * 256 + threadIdx.x;
    int chunk = blockIdx.y;
    union { __hip_bfloat16 h[8]; f32x4 v; } u;
    if (chunk >= 33) {
        f32x4 z = {0.f, 0.f, 0.f, 0.f};
        *(f32x4*)&xp[((size_t)chunk * P2 + p) * 8] = z;
        return;
    }
    BilC bc = bil_coords(p >> 8, p & 255);
#pragma unroll
    for (int j = 0; j < 8; j++) {
        int c = chunk * 8 + j;
        float v = 0.f;
        if (c < 263) {
            const float* src = (c == 0) ? mask
                             : (c < 4)  ? fg + (c - 1) * 16384
                             : (c < 7)  ? bg + (c - 4) * 16384
                             :            feat + (c - 7) * 16384;
            v = bil_eval(src, bc);
        }
        u.h[j] = __float2bfloat16(v);
    }
    *(f32x4*)&xp[((size_t)chunk * P2 + p) * 8] = u.v;
}

// ---------------------------------------------------------------- guide (exact fp32 from fg)
__global__ void guide_make(const float* __restrict__ fg, float* __restrict__ guide) {
    int p = blockIdx.x * 256 + threadIdx.x;
    BilC bc = bil_coords(p >> 8, p & 255);
    float s = bil_eval(fg, bc) + bil_eval(fg + 16384, bc) + bil_eval(fg + 32768, bc);
    guide[p] = s * (128.0f / 3.0f);
}

// ---------------------------------------------------------------- guided filter stats
__global__ void gf_stats(const float* __restrict__ guide, float* __restrict__ meanI,
                         float* __restrict__ varI) {
    int p = blockIdx.x * 256 + threadIdx.x;
    int y = p >> 8, xq = p & 255;
    int y0 = (y - 2 > 0) ? y - 2 : 0, y1 = (y + 2 < 255) ? y + 2 : 255;
    int x0 = (xq - 2 > 0) ? xq - 2 : 0, x1 = (xq + 2 < 255) ? xq + 2 : 255;
    float s = 0.f, ss = 0.f;
    for (int yy = y0; yy <= y1; yy++)
        for (int xx = x0; xx <= x1; xx++) {
            float v = guide[yy * 256 + xx];
            s += v; ss += v * v;
        }
    float inv = 1.0f / (float)((y1 - y0 + 1) * (x1 - x0 + 1));
    float m = s * inv;
    meanI[p] = m;
    varI[p] = ss * inv - m * m;
}

// ---------------------------------------------------------------- merged prep: border zero + 3 weight repacks
__global__ void prep_all(const float* __restrict__ w2, const float* __restrict__ w1,
                         const float* __restrict__ w3,
                         __hip_bfloat16* __restrict__ wpk2, __hip_bfloat16* __restrict__ wpk1,
                         __hip_bfloat16* __restrict__ wpk3, __hip_bfloat16* __restrict__ y1p) {
    int b = blockIdx.x;
    int tid = threadIdx.x;
    if (b < 4225) {                                    // border_zero: 4225*256 = 1081600 chunks
        int idx = b * 256 + tid;
        int p = idx >> 4;
        if (p >= PADW * PADW) return;
        int py = p / PADW, px = p - py * PADW;
        if (py >= 2 && py < 258 && px >= 2 && px < 258) return;
        f32x4 z = {0.f, 0.f, 0.f, 0.f};
        f32x4* dst = (f32x4*)&y1p[(size_t)p * 256 + (idx & 15) * 16];
        dst[0] = z; dst[1] = z;
    } else if (b < 5025) {                             // repack_w2: 800 blocks
        int idx = (b - 4225) * 256 + tid;              // 25*8*16*64 = 204800
        int lane = idx & 63;
        int nb = (idx >> 6) & 15;
        int kt = (idx >> 10) & 7;
        int t  = idx >> 13;
        int oc = nb * 16 + (lane & 15);
        int ic0 = kt * 32 + (lane >> 4) * 8;
        union { __hip_bfloat16 h[8]; f32x4 v; } u;
#pragma unroll
        for (int j = 0; j < 8; j++)
            u.h[j] = __float2bfloat16(w2[(oc * 256 + ic0 + j) * 25 + t]);
        *(f32x4*)&wpk2[(size_t)idx * 8] = u.v;
    } else {
        const float* W; __hip_bfloat16* dst; int K, KT, idx;
        if (b < 5061) { W = w1; dst = wpk1; K = 263; KT = 9; idx = (b - 5025) * 256 + tid; }
        else          { W = w3; dst = wpk3; K = 256; KT = 8; idx = (b - 5061) * 256 + tid; }
        if (idx >= KT * 16 * 64) return;
        int lane = idx & 63;
        int nbg = (idx >> 6) & 15;
        int kt = idx >> 10;
        int oc = nbg * 16 + (lane & 15);
        int ic0 = kt * 32 + (lane >> 4) * 8;
        union { __hip_bfloat16 h[8]; f32x4 v; } u;
#pragma unroll
        for (int j = 0; j < 8; j++) {
            int ic = ic0 + j;
            u.h[j] = (ic < K) ? __float2bfloat16(W[(size_t)oc * K + ic]) : __float2bfloat16(0.f);
        }
        *(f32x4*)&dst[(size_t)idx * 8] = u.v;
    }
}

// ---------------------------------------------------------------- generic 1x1 MFMA GEMM
// MODE 0: bf16 padded NHWC (+relu) -> y1p, via LDS restage (coalesced 16B stores).
// MODE 1: fp32 planar (+relu) -> out.
template<int MODE>
__global__ __launch_bounds__(256) void mfma_1x1(const __hip_bfloat16* __restrict__ xch,
                                                const __hip_bfloat16* __restrict__ wpk,
                                                const float* __restrict__ bias,
                                                void* __restrict__ outp, int KT) {
    __shared__ __align__(16) char smem[MODE == 0 ? 34816 : 32768];
    __hip_bfloat16* Asm0 = (__hip_bfloat16*)smem;                 // [2][128*32]
    __hip_bfloat16* Bsm0 = (__hip_bfloat16*)(smem + 16384);       // [2][8*64*8]
    const int tid = threadIdx.x;
    const int wave = tid >> 6, lane = tid & 63;
    const int q = lane >> 4, m16 = lane & 15;
    const int wm = wave & 1, wn = wave >> 1;
    const int pb = blockIdx.x * 128, oh = blockIdx.y;

    f32x4 acc[4][4] = {};

    auto stA = [&](int kt, int buf) {
#pragma unroll
        for (int it = 0; it < 2; it++) {
            int chb = it * 256 + wave * 64;
            int ch = chb + lane;
            int px = ch >> 2, oct = ch & 3;
            const __hip_bfloat16* src = xch + ((size_t)(kt * 4 + oct) * P2 + pb + px) * 8;
            load16_lds(src, &Asm0[(size_t)buf * 4096 + chb * 8]);
        }
    };
    auto stB = [&](int kt, int buf) {
#pragma unroll
        for (int it = 0; it < 2; it++) {
            int chb = it * 256 + wave * 64;
            int ch = chb + lane;
            int nb = ch >> 6, l = ch & 63;
            const __hip_bfloat16* src = wpk + (((size_t)kt * 16 + oh * 8 + nb) * 64 + l) * 8;
            load16_lds(src, &Bsm0[(size_t)buf * 4096 + chb * 8]);
        }
    };
    stA(0, 0); stB(0, 0);
    int buf = 0;
    for (int kt = 0; kt < KT; kt++) {
        __syncthreads();
        if (kt + 1 < KT) { stA(kt + 1, buf ^ 1); stB(kt + 1, buf ^ 1); }
        frag8 a[4], b[4];
#pragma unroll
        for (int i = 0; i < 4; i++)
            a[i] = *(const frag8*)&Asm0[(size_t)buf * 4096 + ((wm * 4 + i) * 16 + m16) * 32 + q * 8];
#pragma unroll
        for (int j = 0; j < 4; j++)
            b[j] = *(const frag8*)&Bsm0[(size_t)buf * 4096 + ((wn * 4 + j) * 64 + lane) * 8];
#pragma unroll
        for (int i = 0; i < 4; i++)
#pragma unroll
            for (int j = 0; j < 4; j++)
                acc[i][j] = __builtin_amdgcn_mfma_f32_16x16x32_bf16(a[i], b[j], acc[i][j], 0, 0, 0);
        buf ^= 1;
    }
    if (MODE == 0) {
        // restage through LDS: Ct[128 px][136 oc-stride], then coalesced 16B global stores
        __syncthreads();
        __hip_bfloat16* Ct = (__hip_bfloat16*)smem;
#pragma unroll
        for (int j = 0; j < 4; j++) {
            int ocr = (wn * 4 + j) * 16 + m16;
            float bj = bias[oh * 128 + ocr];
#pragma unroll
            for (int i = 0; i < 4; i++) {
                f32x4 v = acc[i][j];
#pragma unroll
                for (int e = 0; e < 4; e++) {
                    int pxr = (wm * 4 + i) * 16 + q * 4 + e;
                    float tv = v[e] + bj;
                    Ct[pxr * 136 + ocr] = __float2bfloat16(tv > 0.f ? tv : 0.f);
                }
            }
        }
        __syncthreads();
        __hip_bfloat16* y1p = (__hip_bfloat16*)outp;
        int colr = (tid & 15) * 8;
#pragma unroll
        for (int it = 0; it < 8; it++) {
            int pxr = it * 16 + (tid >> 4);
            int pix = pb + pxr;
            int py = pix >> 8, px = pix & 255;
            f32x4 val = *(f32x4*)&Ct[pxr * 136 + colr];
            *(f32x4*)&y1p[((size_t)(py + 2) * PADW + px + 2) * 256 + oh * 128 + colr] = val;
        }
    } else {
        float* out = (float*)outp;
#pragma unroll
        for (int j = 0; j < 4; j++) {
            int oc = oh * 128 + (wn * 4 + j) * 16 + m16;
            float bj = bias[oc];
#pragma unroll
            for (int i = 0; i < 4; i++) {
                f32x4 v = acc[i][j];
#pragma unroll
                for (int e = 0; e < 4; e++) { float tv = v[e] + bj; v[e] = tv > 0.f ? tv : 0.f; }
                *(f32x4*)&out[(size_t)oc * P2 + pb + (wm * 4 + i) * 16 + q * 4] = v;
            }
        }
    }
}

// ---------------------------------------------------------------- conv2: 5x5 MFMA implicit GEMM (R5 core)
// out: fp16 [c][p]
__global__ __launch_bounds__(128, 2) void conv5x5_mfma(const __hip_bfloat16* __restrict__ y1p,
                                                       const __hip_bfloat16* __restrict__ wpk,
                                                       const float* __restrict__ bias,
                                                       __half* __restrict__ pf) {
    __shared__ __align__(16) __hip_bfloat16 Asm[2][12 * 20 * 32];  // 2 x 15360 B
    const int tid = threadIdx.x;
    const int wave = tid >> 6;
    const int lane = tid & 63;
    const int q = lane >> 4;
    const int m16 = lane & 15;
    const int bx = blockIdx.x, by = blockIdx.y, oh = blockIdx.z;

    f32x4 acc[4][8] = {};

    auto stageA = [&](int ict, int buf) {
#pragma unroll
        for (int g = 0; g < 8; g++) {
            int grp = g * 2 + wave;
            if (grp >= 15) break;
            int chb = grp * 64;
            int ch = chb + lane;
            int oct = ch & 3, pl = ch >> 2;
            int pc = pl % 20, pr = pl / 20;
            const __hip_bfloat16* src =
                y1p + (size_t)((by * 8 + pr) * PADW + bx * 16 + pc) * 256 + ict * 32 + oct * 8;
            load16_lds(src, &Asm[buf][chb * 8]);
        }
    };
    auto loadB = [&](int s, frag8* dst) {
        int ict = s / 25, tap = s - ict * 25;
        const __hip_bfloat16* base =
            wpk + ((size_t)((tap * 8 + ict) * 16 + oh * 8) * 64 + lane) * 8;
#pragma unroll
        for (int j = 0; j < 8; j++)
            dst[j] = *(const frag8*)(base + (size_t)j * 512);
    };

    frag8 bA[8], bB[8];
    stageA(0, 0);
    loadB(0, bA);
    int abuf = 0;

    auto step = [&](int s, frag8* bcur, frag8* bnxt) {
        int ict = s / 25, tap = s - ict * 25;
        if (tap == 0) __syncthreads();
        if (s + 1 < 200) loadB(s + 1, bnxt);
        if (tap == 24 && ict < 7) stageA(ict + 1, abuf ^ 1);
        int dy = tap / 5, dx = tap - dy * 5;
        frag8 a[4];
#pragma unroll
        for (int i = 0; i < 4; i++)
            a[i] = *(const frag8*)&Asm[abuf][((wave * 4 + i + dy) * 20 + m16 + dx) * 32 + q * 8];
#pragma unroll
        for (int i = 0; i < 4; i++)
#pragma unroll
            for (int j = 0; j < 8; j++)
                acc[i][j] = __builtin_amdgcn_mfma_f32_16x16x32_bf16(a[i], bcur[j], acc[i][j], 0, 0, 0);
        if (tap == 24) abuf ^= 1;
    };
    for (int s = 0; s < 200; s += 2) { step(s, bA, bB); step(s + 1, bB, bA); }

    // epilogue: fp16 out, 8B stores
#pragma unroll
    for (int j = 0; j < 8; j++) {
        int oc = oh * 128 + j * 16 + m16;
        float bj = bias[oc];
#pragma unroll
        for (int i = 0; i < 4; i++) {
            int r = wave * 4 + i;
            f32x4 v = acc[i][j];
            union { __half h[4]; double d; } u;
#pragma unroll
            for (int e = 0; e < 4; e++) {
                float t = v[e] + bj;
                u.h[e] = __float2half(t > 0.f ? t : 0.f);
            }
            *(double*)&pf[(size_t)oc * P2 + (by * 8 + r) * 256 + bx * 16 + q * 4] = u.d;
        }
    }
}

// ---------------------------------------------------------------- guided filter: streaming separable
__global__ __launch_bounds__(256) void gf_stream(const __half* __restrict__ p,
                                                 const float* __restrict__ guide,
                                                 const float* __restrict__ meanI,
                                                 const float* __restrict__ varI,
                                                 __hip_bfloat16* __restrict__ filt) {
    __shared__ float Prow[260], IProw[260], Arow[260], Brow[260];
    const int t = threadIdx.x;
    const int c = blockIdx.y;
    const int Y0 = blockIdx.x * 64;
    const __half* pc = p + (size_t)c * P2;
    if (t < 4) {
        int e = (t < 2) ? t : 256 + t;
        Prow[e] = 0.f; IProw[e] = 0.f; Arow[e] = 0.f; Brow[e] = 0.f;
    }
    int xlo = (t - 2 > 0) ? t - 2 : 0, xhi = (t + 2 < 255) ? t + 2 : 255;
    const float cxr = 1.0f / (float)(xhi - xlo + 1);
    float hp[5] = {0, 0, 0, 0, 0}, hip[5] = {0, 0, 0, 0, 0};
    float ha[5] = {0, 0, 0, 0, 0}, hb[5] = {0, 0, 0, 0, 0};
    float vp = 0.f, vip = 0.f, va = 0.f, vb = 0.f;
    __syncthreads();
    for (int s = 0; s < 72; s++) {
        int yL = Y0 - 4 + s;
        bool okL = ((unsigned)yL < 256u);
        if (okL) {
            float pv = __half2float(pc[yL * 256 + t]);
            Prow[t + 2] = pv;
            IProw[t + 2] = guide[yL * 256 + t] * pv;
        }
        __syncthreads();
        float hpn = 0.f, hipn = 0.f;
        if (okL) {
            hpn  = Prow[t] + Prow[t + 1] + Prow[t + 2] + Prow[t + 3] + Prow[t + 4];
            hipn = IProw[t] + IProw[t + 1] + IProw[t + 2] + IProw[t + 3] + IProw[t + 4];
        }
        vp += hpn - hp[0];  vip += hipn - hip[0];
        hp[0] = hp[1]; hp[1] = hp[2]; hp[2] = hp[3]; hp[3] = hp[4]; hp[4] = hpn;
        hip[0] = hip[1]; hip[1] = hip[2]; hip[2] = hip[3]; hip[3] = hip[4]; hip[4] = hipn;
        int yA = yL - 2;
        float aV = 0.f, bV = 0.f;
        if ((unsigned)yA < 256u && yA >= Y0 - 2) {
            int ylo = (yA - 2 > 0) ? yA - 2 : 0, yhi = (yA + 2 < 255) ? yA + 2 : 255;
            float inv1 = cxr / (float)(yhi - ylo + 1);
            float mI = meanI[yA * 256 + t], vI = varI[yA * 256 + t];
            float mp = vp * inv1, mip = vip * inv1;
            float cov = mip - mI * mp;
            aV = cov / (vI + 0.01f);
            bV = mp - aV * mI;
        }
        Arow[t + 2] = aV;
        Brow[t + 2] = bV;
        __syncthreads();
        float han = Arow[t] + Arow[t + 1] + Arow[t + 2] + Arow[t + 3] + Arow[t + 4];
        float hbn = Brow[t] + Brow[t + 1] + Brow[t + 2] + Brow[t + 3] + Brow[t + 4];
        va += han - ha[0];  vb += hbn - hb[0];
        ha[0] = ha[1]; ha[1] = ha[2]; ha[2] = ha[3]; ha[3] = ha[4]; ha[4] = han;
        hb[0] = hb[1]; hb[1] = hb[2]; hb[2] = hb[3]; hb[3] = hb[4]; hb[4] = hbn;
        int yo = yL - 4;
        if (yo >= Y0 && yo < Y0 + 64 && (unsigned)yo < 256u) {
            int ylo = (yo - 2 > 0) ? yo - 2 : 0, yhi = (yo + 2 < 255) ? yo + 2 : 255;
            float inv2 = cxr / (float)(yhi - ylo + 1);
            float I = guide[yo * 256 + t];
            filt[(size_t)c * P2 + yo * 256 + t] = __float2bfloat16((va * I + vb) * inv2);
        }
    }
}

// ---------------------------------------------------------------- transpose bf16 [c][p] -> chunk-planar [32][P2][8]
__global__ void transpose_cp(const __hip_bfloat16* __restrict__ filt,
                             __hip_bfloat16* __restrict__ filtp) {
    __shared__ __hip_bfloat16 T[8][1024];
    int tid = threadIdx.x;
    int p0 = blockIdx.x * 1024;
    int cg = blockIdx.y;
    for (int i = tid; i < 8192; i += 256) {
        int r = i >> 10, pl = i & 1023;
        T[r][pl] = filt[(size_t)(cg * 8 + r) * P2 + p0 + pl];
    }
    __syncthreads();
    for (int pl = tid; pl < 1024; pl += 256) {
        union { __hip_bfloat16 h[8]; f32x4 v; } u;
#pragma unroll
        for (int j = 0; j < 8; j++) u.h[j] = T[j][pl];
        *(f32x4*)&filtp[((size_t)cg * P2 + p0 + pl) * 8] = u.v;
    }
}

// ---------------------------------------------------------------- mask head (1x1 conv -> sigmoid), 4 px/thread
__global__ void mask_head(const float* __restrict__ feat, const float* __restrict__ wm,
                          const float* __restrict__ bm, float* __restrict__ out) {
    int p4 = (blockIdx.x * 256 + threadIdx.x) * 4;
    float b0 = bm[0];
    f32x4 acc = {b0, b0, b0, b0};
    for (int c = 0; c < 256; c++) {
        f32x4 v = *(const f32x4*)&feat[(size_t)c * P2 + p4];
        float w = wm[c];
#pragma unroll
        for (int e = 0; e < 4; e++) acc[e] += w * v[e];
    }
    f32x4 r;
#pragma unroll
    for (int e = 0; e < 4; e++) r[e] = 1.0f / (1.0f + expf(-acc[e]));
    *(f32x4*)&out[p4] = r;
}

// ---------------------------------------------------------------- launch
extern "C" void kernel_launch(void* const* d_in, const int* in_sizes, int n_in,
                              void* d_out, int out_size, void* d_ws, size_t ws_size,
                              hipStream_t stream) {
    const float* fg   = (const float*)d_in[0];
    const float* bg   = (const float*)d_in[1];
    const float* mask = (const float*)d_in[2];
    const float* feat = (const float*)d_in[3];
    const float* w1   = (const float*)d_in[4];
    const float* b1   = (const float*)d_in[5];
    const float* w2   = (const float*)d_in[6];
    const float* b2   = (const float*)d_in[7];
    const float* w3   = (const float*)d_in[8];
    const float* b3   = (const float*)d_in[9];
    const float* wm   = (const float*)d_in[10];
    const float* bm   = (const float*)d_in[11];
    float* out = (float*)d_out;
    char* w8 = (char*)d_ws;

    __half* pbuf          = (__half*)w8;                         // 33,554,432 B (conv2 out fp16 [c][p])
    __hip_bfloat16* filtp = (__hip_bfloat16*)(w8 + 33554432);    // 33,554,432 B [32][P2][8]
    __hip_bfloat16* xp    = (__hip_bfloat16*)(w8 + 67108864);    // 37,748,736 B [36][P2][8]
    __hip_bfloat16* filt  = (__hip_bfloat16*)(w8 + 67108864);    // alias xp (dead after conv1)
    __hip_bfloat16* y1p   = (__hip_bfloat16*)(w8 + 104857600);   // 34,611,200 B
    __hip_bfloat16* wpk2  = (__hip_bfloat16*)(w8 + 139468800);   // 3,276,800 B
    __hip_bfloat16* wpk1  = (__hip_bfloat16*)(w8 + 142745600);   // 147,456 B
    __hip_bfloat16* wpk3  = (__hip_bfloat16*)(w8 + 142893056);   // 131,072 B
    float* guide = (float*)(w8 + 143024128);
    float* meanI = guide + P2;
    float* varI  = meanI + P2;

    // 1. upsample + concat -> xp
    upsample_x<<<dim3(256, 36), 256, 0, stream>>>(mask, fg, bg, feat, xp);
    // 2. guide + stats
    guide_make<<<256, 256, 0, stream>>>(fg, guide);
    gf_stats<<<256, 256, 0, stream>>>(guide, meanI, varI);
    // 3. merged prep (border zero + 3 repacks)
    prep_all<<<5093, 256, 0, stream>>>(w2, w1, w3, wpk2, wpk1, wpk3, y1p);
    // 4. conv1 (1x1 MFMA) -> y1p
    mfma_1x1<0><<<dim3(512, 2), 256, 0, stream>>>(xp, wpk1, b1, y1p, 9);
    // 5. conv2 (5x5 MFMA) -> pbuf (fp16 [c][p])
    conv5x5_mfma<<<dim3(16, 32, 2), 128, 0, stream>>>(y1p, wpk2, b2, pbuf);
    // 6. guided filter -> filt (bf16 [c][p])
    gf_stream<<<dim3(4, 256), 256, 0, stream>>>(pbuf, guide, meanI, varI, filt);
    // 7. transpose -> filtp
    transpose_cp<<<dim3(64, 32), 256, 0, stream>>>(filt, filtp);
    // 8. conv3 (1x1 MFMA) -> out+P2
    mfma_1x1<1><<<dim3(512, 2), 256, 0, stream>>>(filtp, wpk3, b3, out + P2, 8);
    // 9. mask head -> out[0..P2)
    mask_head<<<64, 256, 0, stream>>>(out + P2, wm, bm, out);
}